// Round 12
// baseline (301.219 us; speedup 1.0000x reference)
//
#include <hip/hip_runtime.h>
#include <cstdint>
#include <cstddef>

#define N_NODES 50000
#define N_EDGES 800000
#define HID 64
#define HEADS 4
#define N_GRAPHS 32
#define N_QUERY 4096
#define N_TILES 3125        // 50000 / 16
#define N_CBLK  782         // ceil(3125/4)

typedef unsigned short ushort_t;
typedef unsigned int uint_t;
typedef __attribute__((ext_vector_type(8))) short short8_t;
typedef __attribute__((ext_vector_type(4))) float f32x4_t;

__device__ __forceinline__ float b2f(ushort_t h) { return __uint_as_float(((uint_t)h) << 16); }
__device__ __forceinline__ ushort_t f2b(float f) {
    uint_t u = __float_as_uint(f);
    uint_t r = (u + 0x7FFFu + ((u >> 16) & 1u)) >> 16;
    return (ushort_t)r;
}

// ---- workspace layout (4-byte element offsets) ----
static constexpr size_t OFF_DEG   = 0;          // int[50000]
static constexpr size_t OFF_GST   = 50016;      // int[33]
static constexpr size_t OFF_OFFS  = 50064;      // int[50001]
static constexpr size_t OFF_RANK  = 100080;     // int[800000]
static constexpr size_t OFF_AL    = 900080;     // float[256]
static constexpr size_t OFF_AR    = 900336;     // float[256]
static constexpr size_t OFF_B     = 900592;     // float[64]
static constexpr size_t OFF_CE    = 900656;     // float[16]
static constexpr size_t OFF_CB    = 900672;     // float[256]
static constexpr size_t OFF_SS    = 900928;     // float[128]
static constexpr size_t OFF_HB2   = 901056;     // float[64]
static constexpr size_t OFF_WQE   = 901120;     // float[4096]
static constexpr size_t OFF_WCVT  = 905216;     // bf16 tiled [40][256][8] -> 40960 float slots
static constexpr size_t OFF_WHT   = 946176;     // bf16 tiled [32][64][8]  -> 8192 float slots
static constexpr size_t OFF_EL    = 954368;     // float[200000]
static constexpr size_t OFF_ER    = 1154368;    // float[200000]
static constexpr size_t OFF_NB    = 1354368;    // bf16[50000*64] -> 1.6M float slots
static constexpr size_t OFF_REC   = 2954368;    // 16B records: int4[800064] -> 3200256 slots
static constexpr size_t OFF_U     = 6154624;    // bf16[50000*320] -> 8M float slots
static constexpr size_t OFF_RST   = 14154624;   // bf16[50000*256] -> 6.4M float slots
static constexpr size_t OFF_X     = 20554624;   // float[3200000]
static constexpr size_t OFF_SCR   = 23754624;   // float[3125*128]
static constexpr size_t OFF_SCR2  = 24154624;   // float[16384]
static constexpr size_t WS_TOTAL  = 24171008;   // elements (~96.7 MB)

// block 0: small algebra (Al/Ar/B/Ce/Cb); blocks 1..16: Wqe; block 17: bounds
__global__ void setup1_kernel(const float* __restrict__ fcw2, const float* __restrict__ fcew2,
                              const float* __restrict__ attl2, const float* __restrict__ attr2,
                              const float* __restrict__ atte2,
                              const float* __restrict__ wpe, const float* __restrict__ bpe,
                              const int* __restrict__ gids,
                              float* __restrict__ Al, float* __restrict__ Ar,
                              float* __restrict__ B, float* __restrict__ Ce,
                              float* __restrict__ Cb, float* __restrict__ Wqe,
                              int* __restrict__ gstart)
{
    int b = blockIdx.x, tid = threadIdx.x;
    if (b == 0) {
        __shared__ float AE[256];
        int c = tid >> 2, h = tid & 3;
        float al = 0.f, ar = 0.f, ae = 0.f;
        for (int d = 0; d < 64; d++) {
            float wl = fcw2[c*256 + h*64 + d];
            float we = fcew2[c*256 + h*64 + d];
            al = fmaf(wl, attl2[h*64 + d], al);
            ar = fmaf(wl, attr2[h*64 + d], ar);
            ae = fmaf(we, atte2[h*64 + d], ae);
        }
        Al[c*4 + h] = al;
        Ar[c*4 + h] = ar;
        AE[c*4 + h] = ae;
        __syncthreads();
        if (tid < 64) {
            int kk = tid >> 2, hh = tid & 3;
            float bb = 0.f;
            for (int d = 0; d < 64; d++) bb = fmaf(wpe[kk*64 + d], AE[d*4 + hh], bb);
            B[kk*4 + hh] = bb;
        }
        if (tid < 4) {
            float ce = 0.f;
            for (int d = 0; d < 64; d++) ce = fmaf(bpe[d], AE[d*4 + tid], ce);
            Ce[tid] = ce;
        }
        {
            float cb = 0.f;
            for (int d = 0; d < 64; d++) cb = fmaf(bpe[d], fcew2[d*256 + tid], cb);
            Cb[tid] = cb;
        }
    } else if (b <= 16) {
        int idx = (b - 1) * 256 + tid;           // 4096
        int hh = idx >> 10, rem = idx & 1023, kk = rem >> 6, cc = rem & 63;
        float w = 0.f;
        for (int d = 0; d < 64; d++) w = fmaf(wpe[kk*64 + d], fcew2[d*256 + hh*64 + cc], w);
        Wqe[idx] = w;
    } else {
        int g = tid;
        if (g <= N_GRAPHS) {
            int lo = 0, hi = N_NODES;
            while (lo < hi) { int mid = (lo + hi) >> 1; if (gids[mid] < g) lo = mid + 1; else hi = mid; }
            gstart[g] = lo;
        }
    }
}

// WcvT tiled builder: thread per (kt,col), writes contiguous short8 (40 blocks)
__global__ void wcvt_kernel(const float* __restrict__ fcw2, const float* __restrict__ Wqe,
                            ushort_t* __restrict__ wcvt)
{
    int idx = blockIdx.x * 256 + threadIdx.x;    // 10240 = 40*256
    int kt = idx >> 8, col = idx & 255;
    int hc = col >> 6;
    short8_t v8;
#pragma unroll
    for (int j = 0; j < 8; j++) {
        int k = kt*8 + j;
        float v;
        if (k < 256) {
            v = ((k >> 6) == hc) ? fcw2[(size_t)(k & 63)*256 + col] : 0.f;
        } else {
            int kq = k - 256, hh = kq >> 4;
            v = (hh == hc) ? Wqe[hh*1024 + (kq & 15)*64 + (col & 63)] : 0.f;
        }
        v8[j] = (short)f2b(v);
    }
    *(short8_t*)&wcvt[(size_t)idx*8] = v8;
}

// nodes(bf16) = node_feat @ Wp + bp ; el/er = nodes @ Al/Ar
__global__ __launch_bounds__(256) void node_proj_kernel(
    const float* __restrict__ nf, const float* __restrict__ wp, const float* __restrict__ bpn,
    const float* __restrict__ Al, const float* __restrict__ Ar,
    ushort_t* __restrict__ nb, float* __restrict__ el, float* __restrict__ er)
{
    __shared__ float rows[4][64];
    int tid = threadIdx.x, w = tid >> 6, lane = tid & 63;
    int n = blockIdx.x * 4 + w;
    rows[w][lane] = nf[(size_t)n*64 + lane];
    __syncthreads();
    float acc = bpn[lane];
    for (int k = 0; k < 64; k++) acc = fmaf(rows[w][k], wp[k*64 + lane], acc);
    nb[(size_t)n*64 + lane] = f2b(acc);
    float pl[4], pr[4];
#pragma unroll
    for (int h = 0; h < 4; h++) { pl[h] = acc * Al[lane*4 + h]; pr[h] = acc * Ar[lane*4 + h]; }
#pragma unroll
    for (int off = 32; off > 0; off >>= 1) {
#pragma unroll
        for (int h = 0; h < 4; h++) {
            pl[h] += __shfl_xor(pl[h], off, 64);
            pr[h] += __shfl_xor(pr[h], off, 64);
        }
    }
    if (lane == 0) {
#pragma unroll
        for (int h = 0; h < 4; h++) { el[(size_t)n*4 + h] = pl[h]; er[(size_t)n*4 + h] = pr[h]; }
    }
}

// deg histogram + per-edge rank within its dst bucket
__global__ void hist_kernel(const int* __restrict__ dst, int* __restrict__ deg,
                            int* __restrict__ rank)
{
    int e = blockIdx.x * 256 + threadIdx.x;
    if (e < N_EDGES) rank[e] = atomicAdd(&deg[dst[e]], 1);
}

__global__ __launch_bounds__(1024) void prefix_kernel(const int* __restrict__ deg,
                                                      int* __restrict__ offs)
{
    __shared__ int wsum[16];
    __shared__ int carry_s;
    int tid = threadIdx.x, lane = tid & 63, w = tid >> 6;
    if (tid == 0) carry_s = 0;
    __syncthreads();
    for (int base = 0; base < N_NODES; base += 1024) {
        int i = base + tid;
        int v = (i < N_NODES) ? deg[i] : 0;
        int incl = v;
#pragma unroll
        for (int off = 1; off < 64; off <<= 1) {
            int y = __shfl_up(incl, off, 64);
            if (lane >= off) incl += y;
        }
        if (lane == 63) wsum[w] = incl;
        __syncthreads();
        int c0 = carry_s;
        int woff = 0;
#pragma unroll
        for (int k = 0; k < 15; k++) woff += (k < w) ? wsum[k] : 0;
        int ex = c0 + woff + incl - v;
        if (i < N_NODES) offs[i] = ex;
        __syncthreads();
        if (tid == 1023) carry_s = c0 + woff + incl;
        __syncthreads();
    }
    if (tid == 0) offs[N_NODES] = carry_s;
}

// 1 edge/thread. 16B record per edge: {l4 bf16x4 (pre-leaky, no er), src, eid}.
__global__ __launch_bounds__(256) void logit_kernel(
    const int* __restrict__ rank, const int* __restrict__ offs,
    const int* __restrict__ src, const int* __restrict__ dst,
    const float* __restrict__ edge_feat, const float* __restrict__ el,
    const float* __restrict__ B, const float* __restrict__ Ce,
    int4* __restrict__ rec)
{
    int e = blockIdx.x * 256 + threadIdx.x;
    if (e >= N_EDGES) return;
    int sn = src[e], dn = dst[e];
    const float4* el4 = (const float4*)el;
    float4 a = el4[sn];
    float l0 = Ce[0] + a.x;
    float l1 = Ce[1] + a.y;
    float l2 = Ce[2] + a.z;
    float l3 = Ce[3] + a.w;
    const float4* ef4 = (const float4*)(edge_feat + (size_t)e * 16);
    float4 e0 = ef4[0], e1 = ef4[1], e2 = ef4[2], e3 = ef4[3];
    float ef[16] = {e0.x,e0.y,e0.z,e0.w, e1.x,e1.y,e1.z,e1.w,
                    e2.x,e2.y,e2.z,e2.w, e3.x,e3.y,e3.z,e3.w};
#pragma unroll
    for (int k = 0; k < 16; k++) {
        float f = ef[k];
        l0 = fmaf(f, B[k*4 + 0], l0);
        l1 = fmaf(f, B[k*4 + 1], l1);
        l2 = fmaf(f, B[k*4 + 2], l2);
        l3 = fmaf(f, B[k*4 + 3], l3);
    }
    int slot = offs[dn] + rank[e];
    uint_t lo01 = (uint_t)f2b(l0) | ((uint_t)f2b(l1) << 16);
    uint_t lo23 = (uint_t)f2b(l2) | ((uint_t)f2b(l3) << 16);
    rec[slot] = make_int4((int)lo01, (int)lo23, sn, e);
}

// 16-lane group per node, 4 nodes/wave; er+leaky+exp here; one-pass softmax
__global__ __launch_bounds__(256) void accum_kernel(
    const int* __restrict__ offs, const int4* __restrict__ rec,
    const float* __restrict__ er, const float* __restrict__ edge_feat,
    const ushort_t* __restrict__ nb, ushort_t* __restrict__ u)
{
    int tid = threadIdx.x;
    int lane = tid & 63;
    int li = lane & 15;
    int node = blockIdx.x * 16 + (tid >> 6) * 4 + ((lane >> 4) & 3);
    int start = offs[node], end = offs[node + 1];
    int deg = end - start;

    float4 er4 = *(const float4*)&er[(size_t)node*4];
    const int4 Z4 = make_int4(0, 0, 0, 0);
    int4 r0 = (li < deg)      ? rec[start + li]      : Z4;
    int4 r1 = (16 + li < deg) ? rec[start + 16 + li] : Z4;

    float pe0[4], pe1[4];
    {
        float l[4] = { b2f((ushort_t)((uint_t)r0.x & 0xffff)) + er4.x,
                       b2f((ushort_t)((uint_t)r0.x >> 16))    + er4.y,
                       b2f((ushort_t)((uint_t)r0.y & 0xffff)) + er4.z,
                       b2f((ushort_t)((uint_t)r0.y >> 16))    + er4.w };
#pragma unroll
        for (int h = 0; h < 4; h++) {
            float lv = (l[h] > 0.f) ? l[h] : 0.2f * l[h];
            pe0[h] = (li < deg) ? __expf(lv) : 0.f;
        }
    }
    {
        float l[4] = { b2f((ushort_t)((uint_t)r1.x & 0xffff)) + er4.x,
                       b2f((ushort_t)((uint_t)r1.x >> 16))    + er4.y,
                       b2f((ushort_t)((uint_t)r1.y & 0xffff)) + er4.z,
                       b2f((ushort_t)((uint_t)r1.y >> 16))    + er4.w };
#pragma unroll
        for (int h = 0; h < 4; h++) {
            float lv = (l[h] > 0.f) ? l[h] : 0.2f * l[h];
            pe1[h] = (16 + li < deg) ? __expf(lv) : 0.f;
        }
    }
    int sn0 = r0.z, eid0 = r0.w;
    int sn1 = r1.z, eid1 = r1.w;

    int mdeg = deg;
#pragma unroll
    for (int off = 1; off < 64; off <<= 1) mdeg = max(mdeg, __shfl_xor(mdeg, off, 64));
    mdeg = __builtin_amdgcn_readfirstlane(mdeg);

    float z0 = 0.f, z1 = 0.f, z2 = 0.f, z3 = 0.f;
    float t[4][4] = {{0.f}};
    float q[4] = {0.f, 0.f, 0.f, 0.f};
    int grpbase = lane & 48;

#pragma unroll 2
    for (int j = 0; j < mdeg; ++j) {
        bool act = j < deg;
        float a0, a1, a2, a3;
        int sn, eid;
        if (j < 32) {
            float v0 = (j < 16) ? pe0[0] : pe1[0];
            float v1 = (j < 16) ? pe0[1] : pe1[1];
            float v2 = (j < 16) ? pe0[2] : pe1[2];
            float v3 = (j < 16) ? pe0[3] : pe1[3];
            int vs = (j < 16) ? sn0 : sn1;
            int ve = (j < 16) ? eid0 : eid1;
            int sl = grpbase | (j & 15);
            a0 = __shfl(v0, sl, 64);
            a1 = __shfl(v1, sl, 64);
            a2 = __shfl(v2, sl, 64);
            a3 = __shfl(v3, sl, 64);
            sn  = __shfl(vs, sl, 64);
            eid = __shfl(ve, sl, 64);
        } else {
            a0 = a1 = a2 = a3 = 0.f;
            sn = 0; eid = 0;
            if (act) {
                int4 rr = rec[start + j];
                float l0 = b2f((ushort_t)((uint_t)rr.x & 0xffff)) + er4.x;
                float l1 = b2f((ushort_t)((uint_t)rr.x >> 16))    + er4.y;
                float l2 = b2f((ushort_t)((uint_t)rr.y & 0xffff)) + er4.z;
                float l3 = b2f((ushort_t)((uint_t)rr.y >> 16))    + er4.w;
                l0 = (l0 > 0.f) ? l0 : 0.2f * l0;
                l1 = (l1 > 0.f) ? l1 : 0.2f * l1;
                l2 = (l2 > 0.f) ? l2 : 0.2f * l2;
                l3 = (l3 > 0.f) ? l3 : 0.2f * l3;
                a0 = __expf(l0); a1 = __expf(l1); a2 = __expf(l2); a3 = __expf(l3);
                sn = rr.z; eid = rr.w;
            }
        }
        z0 += a0; z1 += a1; z2 += a2; z3 += a3;
        ushort4 nv = *(const ushort4*)&nb[(size_t)sn*64 + li*4];
        float nd0 = b2f(nv.x), nd1 = b2f(nv.y), nd2 = b2f(nv.z), nd3 = b2f(nv.w);
        t[0][0] = fmaf(a0, nd0, t[0][0]); t[0][1] = fmaf(a0, nd1, t[0][1]);
        t[0][2] = fmaf(a0, nd2, t[0][2]); t[0][3] = fmaf(a0, nd3, t[0][3]);
        t[1][0] = fmaf(a1, nd0, t[1][0]); t[1][1] = fmaf(a1, nd1, t[1][1]);
        t[1][2] = fmaf(a1, nd2, t[1][2]); t[1][3] = fmaf(a1, nd3, t[1][3]);
        t[2][0] = fmaf(a2, nd0, t[2][0]); t[2][1] = fmaf(a2, nd1, t[2][1]);
        t[2][2] = fmaf(a2, nd2, t[2][2]); t[2][3] = fmaf(a2, nd3, t[2][3]);
        t[3][0] = fmaf(a3, nd0, t[3][0]); t[3][1] = fmaf(a3, nd1, t[3][1]);
        t[3][2] = fmaf(a3, nd2, t[3][2]); t[3][3] = fmaf(a3, nd3, t[3][3]);
        float efv = edge_feat[(size_t)eid*16 + li];
        q[0] = fmaf(a0, efv, q[0]);
        q[1] = fmaf(a1, efv, q[1]);
        q[2] = fmaf(a2, efv, q[2]);
        q[3] = fmaf(a3, efv, q[3]);
    }

    float zinv[4];
    zinv[0] = (z0 > 0.f) ? 1.f / z0 : 0.f;
    zinv[1] = (z1 > 0.f) ? 1.f / z1 : 0.f;
    zinv[2] = (z2 > 0.f) ? 1.f / z2 : 0.f;
    zinv[3] = (z3 > 0.f) ? 1.f / z3 : 0.f;

    ushort_t* up = u + (size_t)node * 320;
#pragma unroll
    for (int h = 0; h < 4; h++) {
        ushort4 tv;
        tv.x = f2b(t[h][0] * zinv[h]); tv.y = f2b(t[h][1] * zinv[h]);
        tv.z = f2b(t[h][2] * zinv[h]); tv.w = f2b(t[h][3] * zinv[h]);
        *(ushort4*)&up[h*64 + li*4] = tv;
        up[256 + h*16 + li] = f2b(q[h] * zinv[h]);
    }
}

// MFMA conv v3: wave per 16-row tile, B read DIRECT from L2-resident tiled wcvt
// (coalesced 256B per 16-lane group), NO barriers, BN partials via shuffles only.
__global__ __launch_bounds__(256) void conv_kernel(
    const ushort_t* __restrict__ u, const ushort_t* __restrict__ wcvt,
    const float* __restrict__ Cb, const float* __restrict__ convb2,
    const int* __restrict__ offs, ushort_t* __restrict__ rst, float* __restrict__ scr)
{
    int tid = threadIdx.x, lane = tid & 63;
    int li = lane & 15, lg = lane >> 4;
    int tile = blockIdx.x * 4 + (tid >> 6);
    if (tile >= N_TILES) return;
    int n0 = tile * 16;

    f32x4_t acc[16];
#pragma unroll
    for (int cb = 0; cb < 16; cb++) acc[cb] = (f32x4_t){0.f, 0.f, 0.f, 0.f};
    const ushort_t* urow = u + (size_t)(n0 + li) * 320 + lg * 8;
    const ushort_t* wbase = wcvt + ((size_t)lg * 256 + li) * 8;

#pragma unroll
    for (int kt = 0; kt < 10; kt++) {
        short8_t a = *(const short8_t*)(urow + kt * 32);
        const ushort_t* wk = wbase + (size_t)kt * 8192;   // (kt*4+lg)*256*8 + li*8
        short8_t b[16];
#pragma unroll
        for (int cb = 0; cb < 16; cb++)
            b[cb] = *(const short8_t*)(wk + (size_t)cb * 128);
#pragma unroll
        for (int cb = 0; cb < 16; cb++)
            acc[cb] = __builtin_amdgcn_mfma_f32_16x16x32_bf16(a, b[cb], acc[cb], 0, 0, 0);
    }

    float fl4[4];
#pragma unroll
    for (int j = 0; j < 4; j++) {
        int n = n0 + lg*4 + j;
        fl4[j] = (offs[n+1] > offs[n]) ? 1.f : 0.f;
    }
    float ds[4] = {0.f, 0.f, 0.f, 0.f};
    float dsq[4] = {0.f, 0.f, 0.f, 0.f};
#pragma unroll
    for (int cb = 0; cb < 16; cb++) {
        int col = cb*16 + li;
        float bias = convb2[col];
        float cbv  = Cb[col];
        float s = 0.f, sq = 0.f;
#pragma unroll
        for (int j = 0; j < 4; j++) {
            float v = acc[cb][j] + bias + fl4[j] * cbv;
            float r = v / (1.f + __expf(-v));
            rst[(size_t)(n0 + lg*4 + j)*256 + col] = f2b(r);
            s += r; sq += r * r;
        }
        s  += __shfl_xor(s, 16, 64);  s  += __shfl_xor(s, 32, 64);
        sq += __shfl_xor(sq, 16, 64); sq += __shfl_xor(sq, 32, 64);
        ds[cb & 3]  += s;
        dsq[cb & 3] += sq;
    }
    if (lg == 0) {
        float* sp = scr + (size_t)tile * 128;
#pragma unroll
        for (int m = 0; m < 4; m++) {
            sp[m*16 + li]      = ds[m];
            sp[64 + m*16 + li] = dsq[m];
        }
    }
}

__global__ __launch_bounds__(128) void scr_reduce_kernel(const float* __restrict__ scr,
                                                         float* __restrict__ scr2)
{
    int b = blockIdx.x, tid = threadIdx.x;
    float s = 0.f;
    for (int r = b; r < N_TILES; r += 128) s += scr[(size_t)r*128 + tid];
    scr2[(size_t)b*128 + tid] = s;
}

__global__ void bn_finalize_kernel(const float* __restrict__ scr2, const float* __restrict__ gamma2,
                                   const float* __restrict__ beta2, float* __restrict__ ss)
{
    __shared__ float part[8][128];
    __shared__ float tot[128];
    int j = threadIdx.x & 127, chunk = threadIdx.x >> 7;
    float t = 0.f;
    for (int b = chunk; b < 128; b += 8) t += scr2[(size_t)b*128 + j];
    part[chunk][j] = t;
    __syncthreads();
    if (threadIdx.x < 128) {
        float sgm = 0.f;
        for (int c = 0; c < 8; c++) sgm += part[c][threadIdx.x];
        tot[threadIdx.x] = sgm;
    }
    __syncthreads();
    if (threadIdx.x < 64) {
        float inv = 1.f / (float)(N_NODES * HEADS);
        float mean = tot[threadIdx.x] * inv;
        float var  = tot[64 + threadIdx.x] * inv - mean * mean;
        float sc = gamma2[threadIdx.x] * rsqrtf(var + 1e-5f);
        ss[threadIdx.x]      = sc;
        ss[64 + threadIdx.x] = beta2[threadIdx.x] - mean * sc;
    }
}

// blocks 0..63: WhT tiled; block 64: hb2
__global__ void head_prep_kernel(const float* __restrict__ ss, const float* __restrict__ headw,
                                 const float* __restrict__ headb,
                                 ushort_t* __restrict__ wht, float* __restrict__ hb2)
{
    int b = blockIdx.x, tid = threadIdx.x;
    if (b < 64) {
        int idx = b * 256 + tid;                 // 16384 entries
        int c = idx >> 8, k = idx & 255;
        wht[(size_t)((k >> 3)*64 + c)*8 + (k & 7)] = f2b(ss[k & 63] * headw[(size_t)k*64 + c]);
    } else if (tid < 64) {
        float s = headb[tid];
        for (int k = 0; k < 256; k++) s += ss[64 + (k & 63)] * headw[(size_t)k*64 + tid];
        hb2[tid] = s;
    }
}

// MFMA head, LDS-staged B (32KB once): x = rst @ Wh' + hb2
__global__ __launch_bounds__(512) void head_kernel(
    const ushort_t* __restrict__ rst, const ushort_t* __restrict__ wht,
    const float* __restrict__ hb2, float* __restrict__ x)
{
    __shared__ ushort_t Bs[16384];       // [32][64][8] = 32 KB
    int tid = threadIdx.x, w = tid >> 6, lane = tid & 63;
    int li = lane & 15, lg = lane >> 4;
    int tile = blockIdx.x * 8 + w;
    bool active = tile < N_TILES;
    int n0 = tile * 16;

#pragma unroll
    for (int s = 0; s < 4; s++) {
        int i = tid + s*512;
        *(short8_t*)&Bs[(size_t)i*8] = *(const short8_t*)(wht + (size_t)i*8);
    }
    __syncthreads();

    if (!active) return;
    f32x4_t acc[4];
#pragma unroll
    for (int cb = 0; cb < 4; cb++) acc[cb] = (f32x4_t){0.f, 0.f, 0.f, 0.f};
    const ushort_t* rrow = rst + (size_t)(n0 + li) * 256 + lg * 8;
#pragma unroll
    for (int kt = 0; kt < 8; kt++) {
        short8_t a = *(const short8_t*)(rrow + kt * 32);
        short8_t b[4];
#pragma unroll
        for (int cb = 0; cb < 4; cb++)
            b[cb] = *(const short8_t*)&Bs[(size_t)((kt*4 + lg)*64 + cb*16 + li)*8];
#pragma unroll
        for (int cb = 0; cb < 4; cb++)
            acc[cb] = __builtin_amdgcn_mfma_f32_16x16x32_bf16(a, b[cb], acc[cb], 0, 0, 0);
    }
#pragma unroll
    for (int cb = 0; cb < 4; cb++) {
        int col = cb*16 + li;
        float hb = hb2[col];
#pragma unroll
        for (int j = 0; j < 4; j++)
            x[(size_t)(n0 + lg*4 + j)*64 + col] = acc[cb][j] + hb;
    }
}

__global__ __launch_bounds__(1024) void pool_kernel(const float* __restrict__ x,
                                                    const int* __restrict__ gstart,
                                                    float* __restrict__ out)
{
    __shared__ float red[16][64];
    int g = blockIdx.x;
    int lane = threadIdx.x & 63, w = threadIdx.x >> 6;
    int s = gstart[g], e = gstart[g + 1];
    float acc = 0.f;
    for (int n = s + w; n < e; n += 16) acc += x[(size_t)n*64 + lane];
    red[w][lane] = acc;
    __syncthreads();
    if (w == 0) {
        float t = 0.f;
#pragma unroll
        for (int k = 0; k < 16; k++) t += red[k][lane];
        float c = (float)(e - s);
        out[(size_t)g*64 + lane] = t / fmaxf(c, 1.f);
    }
}

__global__ void gather_kernel(const float* __restrict__ x, const int* __restrict__ nidx,
                              float* __restrict__ outq)
{
    int i = blockIdx.x * 256 + threadIdx.x;
    if (i < N_QUERY * HID) {
        int q = i >> 6, c = i & 63;
        outq[i] = x[(size_t)nidx[q]*64 + c];
    }
}

extern "C" void kernel_launch(void* const* d_in, const int* in_sizes, int n_in,
                              void* d_out, int out_size, void* d_ws, size_t ws_size,
                              hipStream_t stream)
{
    const float* node_feat   = (const float*)d_in[0];
    const float* edge_feat   = (const float*)d_in[1];
    const float* node_proj_w = (const float*)d_in[2];
    const float* node_proj_b = (const float*)d_in[3];
    const float* edge_proj_w = (const float*)d_in[4];
    const float* edge_proj_b = (const float*)d_in[5];
    const float* fc_w        = (const float*)d_in[6];
    const float* fc_edge_w   = (const float*)d_in[7];
    const float* attn_l      = (const float*)d_in[8];
    const float* attn_r      = (const float*)d_in[9];
    const float* attn_e      = (const float*)d_in[10];
    const float* conv_bias   = (const float*)d_in[11];
    const float* bn_gamma    = (const float*)d_in[12];
    const float* bn_beta     = (const float*)d_in[13];
    const float* head_w      = (const float*)d_in[14];
    const float* head_b      = (const float*)d_in[15];
    const int*   src         = (const int*)d_in[16];
    const int*   dst         = (const int*)d_in[17];
    const int*   gids        = (const int*)d_in[18];
    const int*   nidx        = (const int*)d_in[19];

    if (ws_size < WS_TOTAL * sizeof(float)) return;

    float* ws  = (float*)d_ws;
    float* out = (float*)d_out;

    const int L2 = 2;
    const float* fcw2   = fc_w      + (size_t)L2 * HID * HEADS * HID;
    const float* fcew2  = fc_edge_w + (size_t)L2 * HID * HEADS * HID;
    const float* attl2  = attn_l    + (size_t)L2 * HEADS * HID;
    const float* attr2  = attn_r    + (size_t)L2 * HEADS * HID;
    const float* atte2  = attn_e    + (size_t)L2 * HEADS * HID;
    const float* convb2 = conv_bias + (size_t)L2 * HEADS * HID;
    const float* gamma2 = bn_gamma  + (size_t)L2 * HID;
    const float* beta2  = bn_beta   + (size_t)L2 * HID;

    int*   deg     = (int*)(ws + OFF_DEG);
    int*   gstart  = (int*)(ws + OFF_GST);
    int*   offs    = (int*)(ws + OFF_OFFS);
    int*   rank    = (int*)(ws + OFF_RANK);
    float* Al      = ws + OFF_AL;
    float* Ar      = ws + OFF_AR;
    float* Bm      = ws + OFF_B;
    float* Ce      = ws + OFF_CE;
    float* Cb      = ws + OFF_CB;
    float* ss      = ws + OFF_SS;
    float* hb2     = ws + OFF_HB2;
    float* Wqe     = ws + OFF_WQE;
    ushort_t* wcvt = (ushort_t*)(ws + OFF_WCVT);
    ushort_t* wht  = (ushort_t*)(ws + OFF_WHT);
    float* el      = ws + OFF_EL;
    float* er      = ws + OFF_ER;
    ushort_t* nb   = (ushort_t*)(ws + OFF_NB);
    int4*  rec     = (int4*)(ws + OFF_REC);
    ushort_t* u    = (ushort_t*)(ws + OFF_U);
    ushort_t* rst  = (ushort_t*)(ws + OFF_RST);
    float* x       = ws + OFF_X;
    float* scr     = ws + OFF_SCR;
    float* scr2    = ws + OFF_SCR2;

    hipMemsetAsync(d_ws, 0, N_NODES * sizeof(int), stream);   // deg = 0

    setup1_kernel<<<18, 256, 0, stream>>>(fcw2, fcew2, attl2, attr2, atte2,
                                          edge_proj_w, edge_proj_b, gids,
                                          Al, Ar, Bm, Ce, Cb, Wqe, gstart);
    wcvt_kernel<<<40, 256, 0, stream>>>(fcw2, Wqe, wcvt);
    node_proj_kernel<<<N_NODES/4, 256, 0, stream>>>(node_feat, node_proj_w, node_proj_b,
                                                    Al, Ar, nb, el, er);
    hist_kernel<<<(N_EDGES + 255)/256, 256, 0, stream>>>(dst, deg, rank);
    prefix_kernel<<<1, 1024, 0, stream>>>(deg, offs);
    logit_kernel<<<(N_EDGES + 255)/256, 256, 0, stream>>>(rank, offs, src, dst, edge_feat,
                                                          el, Bm, Ce, rec);
    accum_kernel<<<N_NODES/16, 256, 0, stream>>>(offs, rec, er, edge_feat, nb, u);
    conv_kernel<<<N_CBLK, 256, 0, stream>>>(u, wcvt, Cb, convb2, offs, rst, scr);
    scr_reduce_kernel<<<128, 128, 0, stream>>>(scr, scr2);
    bn_finalize_kernel<<<1, 1024, 0, stream>>>(scr2, gamma2, beta2, ss);
    head_prep_kernel<<<65, 256, 0, stream>>>(ss, head_w, head_b, wht, hb2);
    head_kernel<<<(N_TILES + 7)/8, 512, 0, stream>>>(rst, wht, hb2, x);
    pool_kernel<<<N_GRAPHS, 1024, 0, stream>>>(x, gstart, out);
    gather_kernel<<<(N_QUERY*HID + 255)/256, 256, 0, stream>>>(x, nidx, out + N_GRAPHS*HID);
}

// Round 13
// 289.453 us; speedup vs baseline: 1.0406x; 1.0406x over previous
//
#include <hip/hip_runtime.h>
#include <cstdint>
#include <cstddef>

#define N_NODES 50000
#define N_EDGES 800000
#define HID 64
#define HEADS 4
#define N_GRAPHS 32
#define N_QUERY 4096
#define N_TILES 3125        // 50000 / 16
#define N_CWAVES 1563       // ceil(3125/2), 2 tiles per wave
#define N_CBLK 391          // ceil(1563/4)

typedef unsigned short ushort_t;
typedef unsigned int uint_t;
typedef __attribute__((ext_vector_type(8))) short short8_t;
typedef __attribute__((ext_vector_type(4))) float f32x4_t;

__device__ __forceinline__ float b2f(ushort_t h) { return __uint_as_float(((uint_t)h) << 16); }
__device__ __forceinline__ ushort_t f2b(float f) {
    uint_t u = __float_as_uint(f);
    uint_t r = (u + 0x7FFFu + ((u >> 16) & 1u)) >> 16;
    return (ushort_t)r;
}

// ---- workspace layout (4-byte element offsets) ----
static constexpr size_t OFF_DEG   = 0;          // int[50000]
static constexpr size_t OFF_GST   = 50016;      // int[33]
static constexpr size_t OFF_OFFS  = 50064;      // int[50001]
static constexpr size_t OFF_RANK  = 100080;     // int[800000]
static constexpr size_t OFF_AL    = 900080;     // float[256]
static constexpr size_t OFF_AR    = 900336;     // float[256]
static constexpr size_t OFF_B     = 900592;     // float[64]
static constexpr size_t OFF_CE    = 900656;     // float[16]
static constexpr size_t OFF_CB    = 900672;     // float[256]
static constexpr size_t OFF_SS    = 900928;     // float[128]
static constexpr size_t OFF_HB2   = 901056;     // float[64]
static constexpr size_t OFF_WQE   = 901120;     // float[4096]
static constexpr size_t OFF_WCVT  = 905216;     // bf16 tiled [40][256][8] -> 40960 float slots
static constexpr size_t OFF_WHT   = 946176;     // bf16 tiled [32][64][8]  -> 8192 float slots
static constexpr size_t OFF_EL    = 954368;     // float[200000]
static constexpr size_t OFF_ER    = 1154368;    // float[200000]
static constexpr size_t OFF_NB    = 1354368;    // bf16[50000*64] -> 1.6M float slots
static constexpr size_t OFF_REC   = 2954368;    // 16B records: int4[800064] -> 3200256 slots
static constexpr size_t OFF_U     = 6154624;    // bf16[50000*320] -> 8M float slots
static constexpr size_t OFF_RST   = 14154624;   // bf16[50000*256] -> 6.4M float slots
static constexpr size_t OFF_X     = 20554624;   // float[3200000]
static constexpr size_t OFF_SCR   = 23754624;   // float[1563*128]
static constexpr size_t OFF_SCR2  = 24154624;   // float[16384]
static constexpr size_t WS_TOTAL  = 24171008;   // elements (~96.7 MB)

// block 0: small algebra (Al/Ar/B/Ce/Cb); blocks 1..16: Wqe; block 17: bounds
__global__ void setup1_kernel(const float* __restrict__ fcw2, const float* __restrict__ fcew2,
                              const float* __restrict__ attl2, const float* __restrict__ attr2,
                              const float* __restrict__ atte2,
                              const float* __restrict__ wpe, const float* __restrict__ bpe,
                              const int* __restrict__ gids,
                              float* __restrict__ Al, float* __restrict__ Ar,
                              float* __restrict__ B, float* __restrict__ Ce,
                              float* __restrict__ Cb, float* __restrict__ Wqe,
                              int* __restrict__ gstart)
{
    int b = blockIdx.x, tid = threadIdx.x;
    if (b == 0) {
        __shared__ float AE[256];
        int c = tid >> 2, h = tid & 3;
        float al = 0.f, ar = 0.f, ae = 0.f;
        for (int d = 0; d < 64; d++) {
            float wl = fcw2[c*256 + h*64 + d];
            float we = fcew2[c*256 + h*64 + d];
            al = fmaf(wl, attl2[h*64 + d], al);
            ar = fmaf(wl, attr2[h*64 + d], ar);
            ae = fmaf(we, atte2[h*64 + d], ae);
        }
        Al[c*4 + h] = al;
        Ar[c*4 + h] = ar;
        AE[c*4 + h] = ae;
        __syncthreads();
        if (tid < 64) {
            int kk = tid >> 2, hh = tid & 3;
            float bb = 0.f;
            for (int d = 0; d < 64; d++) bb = fmaf(wpe[kk*64 + d], AE[d*4 + hh], bb);
            B[kk*4 + hh] = bb;
        }
        if (tid < 4) {
            float ce = 0.f;
            for (int d = 0; d < 64; d++) ce = fmaf(bpe[d], AE[d*4 + tid], ce);
            Ce[tid] = ce;
        }
        {
            float cb = 0.f;
            for (int d = 0; d < 64; d++) cb = fmaf(bpe[d], fcew2[d*256 + tid], cb);
            Cb[tid] = cb;
        }
    } else if (b <= 16) {
        int idx = (b - 1) * 256 + tid;           // 4096
        int hh = idx >> 10, rem = idx & 1023, kk = rem >> 6, cc = rem & 63;
        float w = 0.f;
        for (int d = 0; d < 64; d++) w = fmaf(wpe[kk*64 + d], fcew2[d*256 + hh*64 + cc], w);
        Wqe[idx] = w;
    } else {
        int g = tid;
        if (g <= N_GRAPHS) {
            int lo = 0, hi = N_NODES;
            while (lo < hi) { int mid = (lo + hi) >> 1; if (gids[mid] < g) lo = mid + 1; else hi = mid; }
            gstart[g] = lo;
        }
    }
}

// WcvT tiled builder: thread per (kt,col), writes contiguous short8 (40 blocks)
__global__ void wcvt_kernel(const float* __restrict__ fcw2, const float* __restrict__ Wqe,
                            ushort_t* __restrict__ wcvt)
{
    int idx = blockIdx.x * 256 + threadIdx.x;    // 10240 = 40*256
    int kt = idx >> 8, col = idx & 255;
    int hc = col >> 6;
    short8_t v8;
#pragma unroll
    for (int j = 0; j < 8; j++) {
        int k = kt*8 + j;
        float v;
        if (k < 256) {
            v = ((k >> 6) == hc) ? fcw2[(size_t)(k & 63)*256 + col] : 0.f;
        } else {
            int kq = k - 256, hh = kq >> 4;
            v = (hh == hc) ? Wqe[hh*1024 + (kq & 15)*64 + (col & 63)] : 0.f;
        }
        v8[j] = (short)f2b(v);
    }
    *(short8_t*)&wcvt[(size_t)idx*8] = v8;
}

// nodes(bf16) = node_feat @ Wp + bp ; el/er = nodes @ Al/Ar
__global__ __launch_bounds__(256) void node_proj_kernel(
    const float* __restrict__ nf, const float* __restrict__ wp, const float* __restrict__ bpn,
    const float* __restrict__ Al, const float* __restrict__ Ar,
    ushort_t* __restrict__ nb, float* __restrict__ el, float* __restrict__ er)
{
    __shared__ float rows[4][64];
    int tid = threadIdx.x, w = tid >> 6, lane = tid & 63;
    int n = blockIdx.x * 4 + w;
    rows[w][lane] = nf[(size_t)n*64 + lane];
    __syncthreads();
    float acc = bpn[lane];
    for (int k = 0; k < 64; k++) acc = fmaf(rows[w][k], wp[k*64 + lane], acc);
    nb[(size_t)n*64 + lane] = f2b(acc);
    float pl[4], pr[4];
#pragma unroll
    for (int h = 0; h < 4; h++) { pl[h] = acc * Al[lane*4 + h]; pr[h] = acc * Ar[lane*4 + h]; }
#pragma unroll
    for (int off = 32; off > 0; off >>= 1) {
#pragma unroll
        for (int h = 0; h < 4; h++) {
            pl[h] += __shfl_xor(pl[h], off, 64);
            pr[h] += __shfl_xor(pr[h], off, 64);
        }
    }
    if (lane == 0) {
#pragma unroll
        for (int h = 0; h < 4; h++) { el[(size_t)n*4 + h] = pl[h]; er[(size_t)n*4 + h] = pr[h]; }
    }
}

// deg histogram + per-edge rank within its dst bucket
__global__ void hist_kernel(const int* __restrict__ dst, int* __restrict__ deg,
                            int* __restrict__ rank)
{
    int e = blockIdx.x * 256 + threadIdx.x;
    if (e < N_EDGES) rank[e] = atomicAdd(&deg[dst[e]], 1);
}

__global__ __launch_bounds__(1024) void prefix_kernel(const int* __restrict__ deg,
                                                      int* __restrict__ offs)
{
    __shared__ int wsum[16];
    __shared__ int carry_s;
    int tid = threadIdx.x, lane = tid & 63, w = tid >> 6;
    if (tid == 0) carry_s = 0;
    __syncthreads();
    for (int base = 0; base < N_NODES; base += 1024) {
        int i = base + tid;
        int v = (i < N_NODES) ? deg[i] : 0;
        int incl = v;
#pragma unroll
        for (int off = 1; off < 64; off <<= 1) {
            int y = __shfl_up(incl, off, 64);
            if (lane >= off) incl += y;
        }
        if (lane == 63) wsum[w] = incl;
        __syncthreads();
        int c0 = carry_s;
        int woff = 0;
#pragma unroll
        for (int k = 0; k < 15; k++) woff += (k < w) ? wsum[k] : 0;
        int ex = c0 + woff + incl - v;
        if (i < N_NODES) offs[i] = ex;
        __syncthreads();
        if (tid == 1023) carry_s = c0 + woff + incl;
        __syncthreads();
    }
    if (tid == 0) offs[N_NODES] = carry_s;
}

// 1 edge/thread. 16B record per edge: {l4 bf16x4 (pre-leaky, no er), src, eid}.
__global__ __launch_bounds__(256) void logit_kernel(
    const int* __restrict__ rank, const int* __restrict__ offs,
    const int* __restrict__ src, const int* __restrict__ dst,
    const float* __restrict__ edge_feat, const float* __restrict__ el,
    const float* __restrict__ B, const float* __restrict__ Ce,
    int4* __restrict__ rec)
{
    int e = blockIdx.x * 256 + threadIdx.x;
    if (e >= N_EDGES) return;
    int sn = src[e], dn = dst[e];
    const float4* el4 = (const float4*)el;
    float4 a = el4[sn];
    float l0 = Ce[0] + a.x;
    float l1 = Ce[1] + a.y;
    float l2 = Ce[2] + a.z;
    float l3 = Ce[3] + a.w;
    const float4* ef4 = (const float4*)(edge_feat + (size_t)e * 16);
    float4 e0 = ef4[0], e1 = ef4[1], e2 = ef4[2], e3 = ef4[3];
    float ef[16] = {e0.x,e0.y,e0.z,e0.w, e1.x,e1.y,e1.z,e1.w,
                    e2.x,e2.y,e2.z,e2.w, e3.x,e3.y,e3.z,e3.w};
#pragma unroll
    for (int k = 0; k < 16; k++) {
        float f = ef[k];
        l0 = fmaf(f, B[k*4 + 0], l0);
        l1 = fmaf(f, B[k*4 + 1], l1);
        l2 = fmaf(f, B[k*4 + 2], l2);
        l3 = fmaf(f, B[k*4 + 3], l3);
    }
    int slot = offs[dn] + rank[e];
    uint_t lo01 = (uint_t)f2b(l0) | ((uint_t)f2b(l1) << 16);
    uint_t lo23 = (uint_t)f2b(l2) | ((uint_t)f2b(l3) << 16);
    rec[slot] = make_int4((int)lo01, (int)lo23, sn, e);
}

// 16-lane group per node, 4 nodes/wave; er+leaky+exp here; one-pass softmax
__global__ __launch_bounds__(256) void accum_kernel(
    const int* __restrict__ offs, const int4* __restrict__ rec,
    const float* __restrict__ er, const float* __restrict__ edge_feat,
    const ushort_t* __restrict__ nb, ushort_t* __restrict__ u)
{
    int tid = threadIdx.x;
    int lane = tid & 63;
    int li = lane & 15;
    int node = blockIdx.x * 16 + (tid >> 6) * 4 + ((lane >> 4) & 3);
    int start = offs[node], end = offs[node + 1];
    int deg = end - start;

    float4 er4 = *(const float4*)&er[(size_t)node*4];
    const int4 Z4 = make_int4(0, 0, 0, 0);
    int4 r0 = (li < deg)      ? rec[start + li]      : Z4;
    int4 r1 = (16 + li < deg) ? rec[start + 16 + li] : Z4;

    float pe0[4], pe1[4];
    {
        float l[4] = { b2f((ushort_t)((uint_t)r0.x & 0xffff)) + er4.x,
                       b2f((ushort_t)((uint_t)r0.x >> 16))    + er4.y,
                       b2f((ushort_t)((uint_t)r0.y & 0xffff)) + er4.z,
                       b2f((ushort_t)((uint_t)r0.y >> 16))    + er4.w };
#pragma unroll
        for (int h = 0; h < 4; h++) {
            float lv = (l[h] > 0.f) ? l[h] : 0.2f * l[h];
            pe0[h] = (li < deg) ? __expf(lv) : 0.f;
        }
    }
    {
        float l[4] = { b2f((ushort_t)((uint_t)r1.x & 0xffff)) + er4.x,
                       b2f((ushort_t)((uint_t)r1.x >> 16))    + er4.y,
                       b2f((ushort_t)((uint_t)r1.y & 0xffff)) + er4.z,
                       b2f((ushort_t)((uint_t)r1.y >> 16))    + er4.w };
#pragma unroll
        for (int h = 0; h < 4; h++) {
            float lv = (l[h] > 0.f) ? l[h] : 0.2f * l[h];
            pe1[h] = (16 + li < deg) ? __expf(lv) : 0.f;
        }
    }
    int sn0 = r0.z, eid0 = r0.w;
    int sn1 = r1.z, eid1 = r1.w;

    int mdeg = deg;
#pragma unroll
    for (int off = 1; off < 64; off <<= 1) mdeg = max(mdeg, __shfl_xor(mdeg, off, 64));
    mdeg = __builtin_amdgcn_readfirstlane(mdeg);

    float z0 = 0.f, z1 = 0.f, z2 = 0.f, z3 = 0.f;
    float t[4][4] = {{0.f}};
    float q[4] = {0.f, 0.f, 0.f, 0.f};
    int grpbase = lane & 48;

#pragma unroll 2
    for (int j = 0; j < mdeg; ++j) {
        bool act = j < deg;
        float a0, a1, a2, a3;
        int sn, eid;
        if (j < 32) {
            float v0 = (j < 16) ? pe0[0] : pe1[0];
            float v1 = (j < 16) ? pe0[1] : pe1[1];
            float v2 = (j < 16) ? pe0[2] : pe1[2];
            float v3 = (j < 16) ? pe0[3] : pe1[3];
            int vs = (j < 16) ? sn0 : sn1;
            int ve = (j < 16) ? eid0 : eid1;
            int sl = grpbase | (j & 15);
            a0 = __shfl(v0, sl, 64);
            a1 = __shfl(v1, sl, 64);
            a2 = __shfl(v2, sl, 64);
            a3 = __shfl(v3, sl, 64);
            sn  = __shfl(vs, sl, 64);
            eid = __shfl(ve, sl, 64);
        } else {
            a0 = a1 = a2 = a3 = 0.f;
            sn = 0; eid = 0;
            if (act) {
                int4 rr = rec[start + j];
                float l0 = b2f((ushort_t)((uint_t)rr.x & 0xffff)) + er4.x;
                float l1 = b2f((ushort_t)((uint_t)rr.x >> 16))    + er4.y;
                float l2 = b2f((ushort_t)((uint_t)rr.y & 0xffff)) + er4.z;
                float l3 = b2f((ushort_t)((uint_t)rr.y >> 16))    + er4.w;
                l0 = (l0 > 0.f) ? l0 : 0.2f * l0;
                l1 = (l1 > 0.f) ? l1 : 0.2f * l1;
                l2 = (l2 > 0.f) ? l2 : 0.2f * l2;
                l3 = (l3 > 0.f) ? l3 : 0.2f * l3;
                a0 = __expf(l0); a1 = __expf(l1); a2 = __expf(l2); a3 = __expf(l3);
                sn = rr.z; eid = rr.w;
            }
        }
        z0 += a0; z1 += a1; z2 += a2; z3 += a3;
        ushort4 nv = *(const ushort4*)&nb[(size_t)sn*64 + li*4];
        float nd0 = b2f(nv.x), nd1 = b2f(nv.y), nd2 = b2f(nv.z), nd3 = b2f(nv.w);
        t[0][0] = fmaf(a0, nd0, t[0][0]); t[0][1] = fmaf(a0, nd1, t[0][1]);
        t[0][2] = fmaf(a0, nd2, t[0][2]); t[0][3] = fmaf(a0, nd3, t[0][3]);
        t[1][0] = fmaf(a1, nd0, t[1][0]); t[1][1] = fmaf(a1, nd1, t[1][1]);
        t[1][2] = fmaf(a1, nd2, t[1][2]); t[1][3] = fmaf(a1, nd3, t[1][3]);
        t[2][0] = fmaf(a2, nd0, t[2][0]); t[2][1] = fmaf(a2, nd1, t[2][1]);
        t[2][2] = fmaf(a2, nd2, t[2][2]); t[2][3] = fmaf(a2, nd3, t[2][3]);
        t[3][0] = fmaf(a3, nd0, t[3][0]); t[3][1] = fmaf(a3, nd1, t[3][1]);
        t[3][2] = fmaf(a3, nd2, t[3][2]); t[3][3] = fmaf(a3, nd3, t[3][3]);
        float efv = edge_feat[(size_t)eid*16 + li];
        q[0] = fmaf(a0, efv, q[0]);
        q[1] = fmaf(a1, efv, q[1]);
        q[2] = fmaf(a2, efv, q[2]);
        q[3] = fmaf(a3, efv, q[3]);
    }

    float zinv[4];
    zinv[0] = (z0 > 0.f) ? 1.f / z0 : 0.f;
    zinv[1] = (z1 > 0.f) ? 1.f / z1 : 0.f;
    zinv[2] = (z2 > 0.f) ? 1.f / z2 : 0.f;
    zinv[3] = (z3 > 0.f) ? 1.f / z3 : 0.f;

    ushort_t* up = u + (size_t)node * 320;
#pragma unroll
    for (int h = 0; h < 4; h++) {
        ushort4 tv;
        tv.x = f2b(t[h][0] * zinv[h]); tv.y = f2b(t[h][1] * zinv[h]);
        tv.z = f2b(t[h][2] * zinv[h]); tv.w = f2b(t[h][3] * zinv[h]);
        *(ushort4*)&up[h*64 + li*4] = tv;
        up[256 + h*16 + li] = f2b(q[h] * zinv[h]);
    }
}

// MFMA conv v4: wave per 2 tiles (32 rows); ALL A prefetched; cb-outer with
// b[10] batch-prefetch (only one acc pair live). No barriers, no LDS.
__global__ __launch_bounds__(256) void conv_kernel(
    const ushort_t* __restrict__ u, const ushort_t* __restrict__ wcvt,
    const float* __restrict__ Cb, const float* __restrict__ convb2,
    const int* __restrict__ offs, ushort_t* __restrict__ rst, float* __restrict__ scr)
{
    int tid = threadIdx.x, lane = tid & 63;
    int li = lane & 15, lg = lane >> 4;
    int widx = blockIdx.x * 4 + (tid >> 6);
    if (widx >= N_CWAVES) return;
    int tile0 = widx * 2, tile1 = widx * 2 + 1;
    bool t1ok = tile1 < N_TILES;
    int n0 = tile0 * 16;
    int n1 = t1ok ? tile1 * 16 : n0;

    short8_t a0[10], a1[10];
    const ushort_t* urow0 = u + (size_t)(n0 + li) * 320 + lg * 8;
    const ushort_t* urow1 = u + (size_t)(n1 + li) * 320 + lg * 8;
#pragma unroll
    for (int kt = 0; kt < 10; kt++) {
        a0[kt] = *(const short8_t*)(urow0 + kt * 32);
        a1[kt] = *(const short8_t*)(urow1 + kt * 32);
    }

    float fl0[4], fl1[4];
#pragma unroll
    for (int j = 0; j < 4; j++) {
        int na = n0 + lg*4 + j;
        int nbb = n1 + lg*4 + j;
        fl0[j] = (offs[na+1] > offs[na]) ? 1.f : 0.f;
        fl1[j] = (offs[nbb+1] > offs[nbb]) ? 1.f : 0.f;
    }

    const ushort_t* wbase = wcvt + ((size_t)lg * 256 + li) * 8;
    float ds[4] = {0.f, 0.f, 0.f, 0.f};
    float dsq[4] = {0.f, 0.f, 0.f, 0.f};

#pragma unroll 2
    for (int cb = 0; cb < 16; cb++) {
        short8_t b[10];
#pragma unroll
        for (int kt = 0; kt < 10; kt++)
            b[kt] = *(const short8_t*)(wbase + (size_t)kt * 8192 + (size_t)cb * 128);
        f32x4_t acc0 = (f32x4_t){0.f, 0.f, 0.f, 0.f};
        f32x4_t acc1 = (f32x4_t){0.f, 0.f, 0.f, 0.f};
#pragma unroll
        for (int kt = 0; kt < 10; kt++) {
            acc0 = __builtin_amdgcn_mfma_f32_16x16x32_bf16(a0[kt], b[kt], acc0, 0, 0, 0);
            acc1 = __builtin_amdgcn_mfma_f32_16x16x32_bf16(a1[kt], b[kt], acc1, 0, 0, 0);
        }
        int col = cb*16 + li;
        float bias = convb2[col];
        float cbv  = Cb[col];
        float s = 0.f, sq = 0.f;
#pragma unroll
        for (int j = 0; j < 4; j++) {
            float v = acc0[j] + bias + fl0[j] * cbv;
            float r = v / (1.f + __expf(-v));
            rst[(size_t)(n0 + lg*4 + j)*256 + col] = f2b(r);
            s += r; sq += r * r;
        }
        if (t1ok) {
#pragma unroll
            for (int j = 0; j < 4; j++) {
                float v = acc1[j] + bias + fl1[j] * cbv;
                float r = v / (1.f + __expf(-v));
                rst[(size_t)(n1 + lg*4 + j)*256 + col] = f2b(r);
                s += r; sq += r * r;
            }
        }
        s  += __shfl_xor(s, 16, 64);  s  += __shfl_xor(s, 32, 64);
        sq += __shfl_xor(sq, 16, 64); sq += __shfl_xor(sq, 32, 64);
        ds[cb & 3]  += s;
        dsq[cb & 3] += sq;
    }
    if (lg == 0) {
        float* sp = scr + (size_t)widx * 128;
#pragma unroll
        for (int m = 0; m < 4; m++) {
            sp[m*16 + li]      = ds[m];
            sp[64 + m*16 + li] = dsq[m];
        }
    }
}

__global__ __launch_bounds__(128) void scr_reduce_kernel(const float* __restrict__ scr,
                                                         float* __restrict__ scr2)
{
    int b = blockIdx.x, tid = threadIdx.x;
    float s = 0.f;
    for (int r = b; r < N_CWAVES; r += 128) s += scr[(size_t)r*128 + tid];
    scr2[(size_t)b*128 + tid] = s;
}

__global__ void bn_finalize_kernel(const float* __restrict__ scr2, const float* __restrict__ gamma2,
                                   const float* __restrict__ beta2, float* __restrict__ ss)
{
    __shared__ float part[8][128];
    __shared__ float tot[128];
    int j = threadIdx.x & 127, chunk = threadIdx.x >> 7;
    float t = 0.f;
    for (int b = chunk; b < 128; b += 8) t += scr2[(size_t)b*128 + j];
    part[chunk][j] = t;
    __syncthreads();
    if (threadIdx.x < 128) {
        float sgm = 0.f;
        for (int c = 0; c < 8; c++) sgm += part[c][threadIdx.x];
        tot[threadIdx.x] = sgm;
    }
    __syncthreads();
    if (threadIdx.x < 64) {
        float inv = 1.f / (float)(N_NODES * HEADS);
        float mean = tot[threadIdx.x] * inv;
        float var  = tot[64 + threadIdx.x] * inv - mean * mean;
        float sc = gamma2[threadIdx.x] * rsqrtf(var + 1e-5f);
        ss[threadIdx.x]      = sc;
        ss[64 + threadIdx.x] = beta2[threadIdx.x] - mean * sc;
    }
}

// blocks 0..63: WhT tiled; block 64: hb2
__global__ void head_prep_kernel(const float* __restrict__ ss, const float* __restrict__ headw,
                                 const float* __restrict__ headb,
                                 ushort_t* __restrict__ wht, float* __restrict__ hb2)
{
    int b = blockIdx.x, tid = threadIdx.x;
    if (b < 64) {
        int idx = b * 256 + tid;                 // 16384 entries
        int c = idx >> 8, k = idx & 255;
        wht[(size_t)((k >> 3)*64 + c)*8 + (k & 7)] = f2b(ss[k & 63] * headw[(size_t)k*64 + c]);
    } else if (tid < 64) {
        float s = headb[tid];
        for (int k = 0; k < 256; k++) s += ss[64 + (k & 63)] * headw[(size_t)k*64 + tid];
        hb2[tid] = s;
    }
}

// MFMA head, LDS-staged B (32KB once): x = rst @ Wh' + hb2
__global__ __launch_bounds__(512) void head_kernel(
    const ushort_t* __restrict__ rst, const ushort_t* __restrict__ wht,
    const float* __restrict__ hb2, float* __restrict__ x)
{
    __shared__ ushort_t Bs[16384];       // [32][64][8] = 32 KB
    int tid = threadIdx.x, w = tid >> 6, lane = tid & 63;
    int li = lane & 15, lg = lane >> 4;
    int tile = blockIdx.x * 8 + w;
    bool active = tile < N_TILES;
    int n0 = tile * 16;

#pragma unroll
    for (int s = 0; s < 4; s++) {
        int i = tid + s*512;
        *(short8_t*)&Bs[(size_t)i*8] = *(const short8_t*)(wht + (size_t)i*8);
    }
    __syncthreads();

    if (!active) return;
    f32x4_t acc[4];
#pragma unroll
    for (int cb = 0; cb < 4; cb++) acc[cb] = (f32x4_t){0.f, 0.f, 0.f, 0.f};
    const ushort_t* rrow = rst + (size_t)(n0 + li) * 256 + lg * 8;
#pragma unroll
    for (int kt = 0; kt < 8; kt++) {
        short8_t a = *(const short8_t*)(rrow + kt * 32);
        short8_t b[4];
#pragma unroll
        for (int cb = 0; cb < 4; cb++)
            b[cb] = *(const short8_t*)&Bs[(size_t)((kt*4 + lg)*64 + cb*16 + li)*8];
#pragma unroll
        for (int cb = 0; cb < 4; cb++)
            acc[cb] = __builtin_amdgcn_mfma_f32_16x16x32_bf16(a, b[cb], acc[cb], 0, 0, 0);
    }
#pragma unroll
    for (int cb = 0; cb < 4; cb++) {
        int col = cb*16 + li;
        float hb = hb2[col];
#pragma unroll
        for (int j = 0; j < 4; j++)
            x[(size_t)(n0 + lg*4 + j)*64 + col] = acc[cb][j] + hb;
    }
}

__global__ __launch_bounds__(1024) void pool_kernel(const float* __restrict__ x,
                                                    const int* __restrict__ gstart,
                                                    float* __restrict__ out)
{
    __shared__ float red[16][64];
    int g = blockIdx.x;
    int lane = threadIdx.x & 63, w = threadIdx.x >> 6;
    int s = gstart[g], e = gstart[g + 1];
    float acc = 0.f;
    for (int n = s + w; n < e; n += 16) acc += x[(size_t)n*64 + lane];
    red[w][lane] = acc;
    __syncthreads();
    if (w == 0) {
        float t = 0.f;
#pragma unroll
        for (int k = 0; k < 16; k++) t += red[k][lane];
        float c = (float)(e - s);
        out[(size_t)g*64 + lane] = t / fmaxf(c, 1.f);
    }
}

__global__ void gather_kernel(const float* __restrict__ x, const int* __restrict__ nidx,
                              float* __restrict__ outq)
{
    int i = blockIdx.x * 256 + threadIdx.x;
    if (i < N_QUERY * HID) {
        int q = i >> 6, c = i & 63;
        outq[i] = x[(size_t)nidx[q]*64 + c];
    }
}

extern "C" void kernel_launch(void* const* d_in, const int* in_sizes, int n_in,
                              void* d_out, int out_size, void* d_ws, size_t ws_size,
                              hipStream_t stream)
{
    const float* node_feat   = (const float*)d_in[0];
    const float* edge_feat   = (const float*)d_in[1];
    const float* node_proj_w = (const float*)d_in[2];
    const float* node_proj_b = (const float*)d_in[3];
    const float* edge_proj_w = (const float*)d_in[4];
    const float* edge_proj_b = (const float*)d_in[5];
    const float* fc_w        = (const float*)d_in[6];
    const float* fc_edge_w   = (const float*)d_in[7];
    const float* attn_l      = (const float*)d_in[8];
    const float* attn_r      = (const float*)d_in[9];
    const float* attn_e      = (const float*)d_in[10];
    const float* conv_bias   = (const float*)d_in[11];
    const float* bn_gamma    = (const float*)d_in[12];
    const float* bn_beta     = (const float*)d_in[13];
    const float* head_w      = (const float*)d_in[14];
    const float* head_b      = (const float*)d_in[15];
    const int*   src         = (const int*)d_in[16];
    const int*   dst         = (const int*)d_in[17];
    const int*   gids        = (const int*)d_in[18];
    const int*   nidx        = (const int*)d_in[19];

    if (ws_size < WS_TOTAL * sizeof(float)) return;

    float* ws  = (float*)d_ws;
    float* out = (float*)d_out;

    const int L2 = 2;
    const float* fcw2   = fc_w      + (size_t)L2 * HID * HEADS * HID;
    const float* fcew2  = fc_edge_w + (size_t)L2 * HID * HEADS * HID;
    const float* attl2  = attn_l    + (size_t)L2 * HEADS * HID;
    const float* attr2  = attn_r    + (size_t)L2 * HEADS * HID;
    const float* atte2  = attn_e    + (size_t)L2 * HEADS * HID;
    const float* convb2 = conv_bias + (size_t)L2 * HEADS * HID;
    const float* gamma2 = bn_gamma  + (size_t)L2 * HID;
    const float* beta2  = bn_beta   + (size_t)L2 * HID;

    int*   deg     = (int*)(ws + OFF_DEG);
    int*   gstart  = (int*)(ws + OFF_GST);
    int*   offs    = (int*)(ws + OFF_OFFS);
    int*   rank    = (int*)(ws + OFF_RANK);
    float* Al      = ws + OFF_AL;
    float* Ar      = ws + OFF_AR;
    float* Bm      = ws + OFF_B;
    float* Ce      = ws + OFF_CE;
    float* Cb      = ws + OFF_CB;
    float* ss      = ws + OFF_SS;
    float* hb2     = ws + OFF_HB2;
    float* Wqe     = ws + OFF_WQE;
    ushort_t* wcvt = (ushort_t*)(ws + OFF_WCVT);
    ushort_t* wht  = (ushort_t*)(ws + OFF_WHT);
    float* el      = ws + OFF_EL;
    float* er      = ws + OFF_ER;
    ushort_t* nb   = (ushort_t*)(ws + OFF_NB);
    int4*  rec     = (int4*)(ws + OFF_REC);
    ushort_t* u    = (ushort_t*)(ws + OFF_U);
    ushort_t* rst  = (ushort_t*)(ws + OFF_RST);
    float* x       = ws + OFF_X;
    float* scr     = ws + OFF_SCR;
    float* scr2    = ws + OFF_SCR2;

    hipMemsetAsync(d_ws, 0, N_NODES * sizeof(int), stream);   // deg = 0

    setup1_kernel<<<18, 256, 0, stream>>>(fcw2, fcew2, attl2, attr2, atte2,
                                          edge_proj_w, edge_proj_b, gids,
                                          Al, Ar, Bm, Ce, Cb, Wqe, gstart);
    wcvt_kernel<<<40, 256, 0, stream>>>(fcw2, Wqe, wcvt);
    node_proj_kernel<<<N_NODES/4, 256, 0, stream>>>(node_feat, node_proj_w, node_proj_b,
                                                    Al, Ar, nb, el, er);
    hist_kernel<<<(N_EDGES + 255)/256, 256, 0, stream>>>(dst, deg, rank);
    prefix_kernel<<<1, 1024, 0, stream>>>(deg, offs);
    logit_kernel<<<(N_EDGES + 255)/256, 256, 0, stream>>>(rank, offs, src, dst, edge_feat,
                                                          el, Bm, Ce, rec);
    accum_kernel<<<N_NODES/16, 256, 0, stream>>>(offs, rec, er, edge_feat, nb, u);
    conv_kernel<<<N_CBLK, 256, 0, stream>>>(u, wcvt, Cb, convb2, offs, rst, scr);
    scr_reduce_kernel<<<128, 128, 0, stream>>>(scr, scr2);
    bn_finalize_kernel<<<1, 1024, 0, stream>>>(scr2, gamma2, beta2, ss);
    head_prep_kernel<<<65, 256, 0, stream>>>(ss, head_w, head_b, wht, hb2);
    head_kernel<<<(N_TILES + 7)/8, 512, 0, stream>>>(rst, wht, hb2, x);
    pool_kernel<<<N_GRAPHS, 1024, 0, stream>>>(x, gstart, out);
    gather_kernel<<<(N_QUERY*HID + 255)/256, 256, 0, stream>>>(x, nidx, out + N_GRAPHS*HID);
}

// Round 14
// 252.775 us; speedup vs baseline: 1.1916x; 1.1451x over previous
//
#include <hip/hip_runtime.h>
#include <cstdint>
#include <cstddef>

#define N_NODES 50000
#define N_EDGES 800000
#define HID 64
#define HEADS 4
#define N_GRAPHS 32
#define N_QUERY 4096
#define N_TILES 3125        // 50000 / 16
#define N_CWAVES 1563       // ceil(3125/2), 2 tiles per wave
#define N_CBLK 391          // ceil(1563/4)
#define N_SBLK 49           // ceil(50000/1024)

typedef unsigned short ushort_t;
typedef unsigned int uint_t;
typedef __attribute__((ext_vector_type(8))) short short8_t;
typedef __attribute__((ext_vector_type(4))) float f32x4_t;

__device__ __forceinline__ float b2f(ushort_t h) { return __uint_as_float(((uint_t)h) << 16); }
__device__ __forceinline__ ushort_t f2b(float f) {
    uint_t u = __float_as_uint(f);
    uint_t r = (u + 0x7FFFu + ((u >> 16) & 1u)) >> 16;
    return (ushort_t)r;
}

// ---- workspace layout (4-byte element offsets) ----
static constexpr size_t OFF_DEG   = 0;          // int[50000]
static constexpr size_t OFF_GST   = 50016;      // int[33]
static constexpr size_t OFF_OFFS  = 50064;      // int[50001]
static constexpr size_t OFF_RANK  = 100080;     // int[800000]
static constexpr size_t OFF_AL    = 900080;     // float[256]
static constexpr size_t OFF_AR    = 900336;     // float[256]
static constexpr size_t OFF_B     = 900592;     // float[64]
static constexpr size_t OFF_CE    = 900656;     // float[16]
static constexpr size_t OFF_CB    = 900672;     // float[256]
static constexpr size_t OFF_SS    = 900928;     // float[128]
static constexpr size_t OFF_HB2   = 901056;     // float[64]
static constexpr size_t OFF_WQE   = 901120;     // float[4096]
static constexpr size_t OFF_WCVT  = 905216;     // bf16 tiled [40][256][8] -> 40960 float slots
static constexpr size_t OFF_WHT   = 946176;     // bf16 tiled [32][64][8]  -> 8192 float slots
static constexpr size_t OFF_EL    = 954368;     // float[200000]
static constexpr size_t OFF_ER    = 1154368;    // float[200000]
static constexpr size_t OFF_NB    = 1354368;    // bf16[50000*64] -> 1.6M float slots
static constexpr size_t OFF_REC   = 2954368;    // 16B records: int4[800064] -> 3200256 slots
static constexpr size_t OFF_U     = 6154624;    // bf16[50000*320] -> 8M float slots
static constexpr size_t OFF_RST   = 14154624;   // bf16[50000*256] -> 6.4M float slots
static constexpr size_t OFF_X     = 20554624;   // float[3200000]
static constexpr size_t OFF_SCR   = 23754624;   // float[1563*128]
static constexpr size_t OFF_SCR2  = 24154624;   // float[16384]
static constexpr size_t OFF_BSUM  = 24171008;   // int[64]
static constexpr size_t WS_TOTAL  = 24171072;   // elements (~96.7 MB)

// block 0: small algebra (Al/Ar/B/Ce/Cb); blocks 1..16: Wqe; block 17: bounds
__global__ void setup1_kernel(const float* __restrict__ fcw2, const float* __restrict__ fcew2,
                              const float* __restrict__ attl2, const float* __restrict__ attr2,
                              const float* __restrict__ atte2,
                              const float* __restrict__ wpe, const float* __restrict__ bpe,
                              const int* __restrict__ gids,
                              float* __restrict__ Al, float* __restrict__ Ar,
                              float* __restrict__ B, float* __restrict__ Ce,
                              float* __restrict__ Cb, float* __restrict__ Wqe,
                              int* __restrict__ gstart)
{
    int b = blockIdx.x, tid = threadIdx.x;
    if (b == 0) {
        __shared__ float AE[256];
        int c = tid >> 2, h = tid & 3;
        float al = 0.f, ar = 0.f, ae = 0.f;
        for (int d = 0; d < 64; d++) {
            float wl = fcw2[c*256 + h*64 + d];
            float we = fcew2[c*256 + h*64 + d];
            al = fmaf(wl, attl2[h*64 + d], al);
            ar = fmaf(wl, attr2[h*64 + d], ar);
            ae = fmaf(we, atte2[h*64 + d], ae);
        }
        Al[c*4 + h] = al;
        Ar[c*4 + h] = ar;
        AE[c*4 + h] = ae;
        __syncthreads();
        if (tid < 64) {
            int kk = tid >> 2, hh = tid & 3;
            float bb = 0.f;
            for (int d = 0; d < 64; d++) bb = fmaf(wpe[kk*64 + d], AE[d*4 + hh], bb);
            B[kk*4 + hh] = bb;
        }
        if (tid < 4) {
            float ce = 0.f;
            for (int d = 0; d < 64; d++) ce = fmaf(bpe[d], AE[d*4 + tid], ce);
            Ce[tid] = ce;
        }
        {
            float cb = 0.f;
            for (int d = 0; d < 64; d++) cb = fmaf(bpe[d], fcew2[d*256 + tid], cb);
            Cb[tid] = cb;
        }
    } else if (b <= 16) {
        int idx = (b - 1) * 256 + tid;           // 4096
        int hh = idx >> 10, rem = idx & 1023, kk = rem >> 6, cc = rem & 63;
        float w = 0.f;
        for (int d = 0; d < 64; d++) w = fmaf(wpe[kk*64 + d], fcew2[d*256 + hh*64 + cc], w);
        Wqe[idx] = w;
    } else {
        int g = tid;
        if (g <= N_GRAPHS) {
            int lo = 0, hi = N_NODES;
            while (lo < hi) { int mid = (lo + hi) >> 1; if (gids[mid] < g) lo = mid + 1; else hi = mid; }
            gstart[g] = lo;
        }
    }
}

// WcvT tiled builder: thread per (kt,col), writes contiguous short8 (40 blocks)
__global__ void wcvt_kernel(const float* __restrict__ fcw2, const float* __restrict__ Wqe,
                            ushort_t* __restrict__ wcvt)
{
    int idx = blockIdx.x * 256 + threadIdx.x;    // 10240 = 40*256
    int kt = idx >> 8, col = idx & 255;
    int hc = col >> 6;
    short8_t v8;
#pragma unroll
    for (int j = 0; j < 8; j++) {
        int k = kt*8 + j;
        float v;
        if (k < 256) {
            v = ((k >> 6) == hc) ? fcw2[(size_t)(k & 63)*256 + col] : 0.f;
        } else {
            int kq = k - 256, hh = kq >> 4;
            v = (hh == hc) ? Wqe[hh*1024 + (kq & 15)*64 + (col & 63)] : 0.f;
        }
        v8[j] = (short)f2b(v);
    }
    *(short8_t*)&wcvt[(size_t)idx*8] = v8;
}

// nodes(bf16) = node_feat @ Wp + bp ; el/er = nodes @ Al/Ar
__global__ __launch_bounds__(256) void node_proj_kernel(
    const float* __restrict__ nf, const float* __restrict__ wp, const float* __restrict__ bpn,
    const float* __restrict__ Al, const float* __restrict__ Ar,
    ushort_t* __restrict__ nb, float* __restrict__ el, float* __restrict__ er)
{
    __shared__ float rows[4][64];
    int tid = threadIdx.x, w = tid >> 6, lane = tid & 63;
    int n = blockIdx.x * 4 + w;
    rows[w][lane] = nf[(size_t)n*64 + lane];
    __syncthreads();
    float acc = bpn[lane];
    for (int k = 0; k < 64; k++) acc = fmaf(rows[w][k], wp[k*64 + lane], acc);
    nb[(size_t)n*64 + lane] = f2b(acc);
    float pl[4], pr[4];
#pragma unroll
    for (int h = 0; h < 4; h++) { pl[h] = acc * Al[lane*4 + h]; pr[h] = acc * Ar[lane*4 + h]; }
#pragma unroll
    for (int off = 32; off > 0; off >>= 1) {
#pragma unroll
        for (int h = 0; h < 4; h++) {
            pl[h] += __shfl_xor(pl[h], off, 64);
            pr[h] += __shfl_xor(pr[h], off, 64);
        }
    }
    if (lane == 0) {
#pragma unroll
        for (int h = 0; h < 4; h++) { el[(size_t)n*4 + h] = pl[h]; er[(size_t)n*4 + h] = pr[h]; }
    }
}

// deg histogram + per-edge rank within its dst bucket
__global__ void hist_kernel(const int* __restrict__ dst, int* __restrict__ deg,
                            int* __restrict__ rank)
{
    int e = blockIdx.x * 256 + threadIdx.x;
    if (e < N_EDGES) rank[e] = atomicAdd(&deg[dst[e]], 1);
}

// multi-block scan phase 1: block-local exclusive scan + block sums (49 blocks)
__global__ __launch_bounds__(1024) void scan1_kernel(const int* __restrict__ deg,
                                                     int* __restrict__ offs,
                                                     int* __restrict__ bsum)
{
    __shared__ int wsum[16];
    int b = blockIdx.x, tid = threadIdx.x, lane = tid & 63, w = tid >> 6;
    int i = b * 1024 + tid;
    int v = (i < N_NODES) ? deg[i] : 0;
    int incl = v;
#pragma unroll
    for (int off = 1; off < 64; off <<= 1) {
        int y = __shfl_up(incl, off, 64);
        if (lane >= off) incl += y;
    }
    if (lane == 63) wsum[w] = incl;
    __syncthreads();
    int woff = 0;
#pragma unroll
    for (int k = 0; k < 15; k++) woff += (k < w) ? wsum[k] : 0;
    if (i < N_NODES) offs[i] = woff + incl - v;
    if (tid == 1023) bsum[b] = woff + incl;
}

// phase 2: one wave scans the 49 block sums -> exclusive bases, writes total
__global__ void scan2_kernel(int* __restrict__ bsum, int* __restrict__ offs)
{
    int tid = threadIdx.x;  // 64
    int v = (tid < N_SBLK) ? bsum[tid] : 0;
    int incl = v;
#pragma unroll
    for (int off = 1; off < 64; off <<= 1) {
        int y = __shfl_up(incl, off, 64);
        if (tid >= off) incl += y;
    }
    if (tid < N_SBLK) bsum[tid] = incl - v;
    if (tid == N_SBLK - 1) offs[N_NODES] = incl;
}

// phase 3: add block bases (49 blocks)
__global__ __launch_bounds__(1024) void scan3_kernel(int* __restrict__ offs,
                                                     const int* __restrict__ bsum)
{
    int i = blockIdx.x * 1024 + threadIdx.x;
    if (i < N_NODES) offs[i] += bsum[blockIdx.x];
}

// 1 edge/thread. 16B record per edge: {l4 bf16x4 (pre-leaky, no er), src, eid}.
__global__ __launch_bounds__(256) void logit_kernel(
    const int* __restrict__ rank, const int* __restrict__ offs,
    const int* __restrict__ src, const int* __restrict__ dst,
    const float* __restrict__ edge_feat, const float* __restrict__ el,
    const float* __restrict__ B, const float* __restrict__ Ce,
    int4* __restrict__ rec)
{
    int e = blockIdx.x * 256 + threadIdx.x;
    if (e >= N_EDGES) return;
    int sn = src[e], dn = dst[e];
    const float4* el4 = (const float4*)el;
    float4 a = el4[sn];
    float l0 = Ce[0] + a.x;
    float l1 = Ce[1] + a.y;
    float l2 = Ce[2] + a.z;
    float l3 = Ce[3] + a.w;
    const float4* ef4 = (const float4*)(edge_feat + (size_t)e * 16);
    float4 e0 = ef4[0], e1 = ef4[1], e2 = ef4[2], e3 = ef4[3];
    float ef[16] = {e0.x,e0.y,e0.z,e0.w, e1.x,e1.y,e1.z,e1.w,
                    e2.x,e2.y,e2.z,e2.w, e3.x,e3.y,e3.z,e3.w};
#pragma unroll
    for (int k = 0; k < 16; k++) {
        float f = ef[k];
        l0 = fmaf(f, B[k*4 + 0], l0);
        l1 = fmaf(f, B[k*4 + 1], l1);
        l2 = fmaf(f, B[k*4 + 2], l2);
        l3 = fmaf(f, B[k*4 + 3], l3);
    }
    int slot = offs[dn] + rank[e];
    uint_t lo01 = (uint_t)f2b(l0) | ((uint_t)f2b(l1) << 16);
    uint_t lo23 = (uint_t)f2b(l2) | ((uint_t)f2b(l3) << 16);
    rec[slot] = make_int4((int)lo01, (int)lo23, sn, e);
}

// 16-lane group per node, 4 nodes/wave; er+leaky+exp here; one-pass softmax
__global__ __launch_bounds__(256) void accum_kernel(
    const int* __restrict__ offs, const int4* __restrict__ rec,
    const float* __restrict__ er, const float* __restrict__ edge_feat,
    const ushort_t* __restrict__ nb, ushort_t* __restrict__ u)
{
    int tid = threadIdx.x;
    int lane = tid & 63;
    int li = lane & 15;
    int node = blockIdx.x * 16 + (tid >> 6) * 4 + ((lane >> 4) & 3);
    int start = offs[node], end = offs[node + 1];
    int deg = end - start;

    float4 er4 = *(const float4*)&er[(size_t)node*4];
    const int4 Z4 = make_int4(0, 0, 0, 0);
    int4 r0 = (li < deg)      ? rec[start + li]      : Z4;
    int4 r1 = (16 + li < deg) ? rec[start + 16 + li] : Z4;

    float pe0[4], pe1[4];
    {
        float l[4] = { b2f((ushort_t)((uint_t)r0.x & 0xffff)) + er4.x,
                       b2f((ushort_t)((uint_t)r0.x >> 16))    + er4.y,
                       b2f((ushort_t)((uint_t)r0.y & 0xffff)) + er4.z,
                       b2f((ushort_t)((uint_t)r0.y >> 16))    + er4.w };
#pragma unroll
        for (int h = 0; h < 4; h++) {
            float lv = (l[h] > 0.f) ? l[h] : 0.2f * l[h];
            pe0[h] = (li < deg) ? __expf(lv) : 0.f;
        }
    }
    {
        float l[4] = { b2f((ushort_t)((uint_t)r1.x & 0xffff)) + er4.x,
                       b2f((ushort_t)((uint_t)r1.x >> 16))    + er4.y,
                       b2f((ushort_t)((uint_t)r1.y & 0xffff)) + er4.z,
                       b2f((ushort_t)((uint_t)r1.y >> 16))    + er4.w };
#pragma unroll
        for (int h = 0; h < 4; h++) {
            float lv = (l[h] > 0.f) ? l[h] : 0.2f * l[h];
            pe1[h] = (16 + li < deg) ? __expf(lv) : 0.f;
        }
    }
    int sn0 = r0.z, eid0 = r0.w;
    int sn1 = r1.z, eid1 = r1.w;

    int mdeg = deg;
#pragma unroll
    for (int off = 1; off < 64; off <<= 1) mdeg = max(mdeg, __shfl_xor(mdeg, off, 64));
    mdeg = __builtin_amdgcn_readfirstlane(mdeg);

    float z0 = 0.f, z1 = 0.f, z2 = 0.f, z3 = 0.f;
    float t[4][4] = {{0.f}};
    float q[4] = {0.f, 0.f, 0.f, 0.f};
    int grpbase = lane & 48;

#pragma unroll 2
    for (int j = 0; j < mdeg; ++j) {
        bool act = j < deg;
        float a0, a1, a2, a3;
        int sn, eid;
        if (j < 32) {
            float v0 = (j < 16) ? pe0[0] : pe1[0];
            float v1 = (j < 16) ? pe0[1] : pe1[1];
            float v2 = (j < 16) ? pe0[2] : pe1[2];
            float v3 = (j < 16) ? pe0[3] : pe1[3];
            int vs = (j < 16) ? sn0 : sn1;
            int ve = (j < 16) ? eid0 : eid1;
            int sl = grpbase | (j & 15);
            a0 = __shfl(v0, sl, 64);
            a1 = __shfl(v1, sl, 64);
            a2 = __shfl(v2, sl, 64);
            a3 = __shfl(v3, sl, 64);
            sn  = __shfl(vs, sl, 64);
            eid = __shfl(ve, sl, 64);
        } else {
            a0 = a1 = a2 = a3 = 0.f;
            sn = 0; eid = 0;
            if (act) {
                int4 rr = rec[start + j];
                float l0 = b2f((ushort_t)((uint_t)rr.x & 0xffff)) + er4.x;
                float l1 = b2f((ushort_t)((uint_t)rr.x >> 16))    + er4.y;
                float l2 = b2f((ushort_t)((uint_t)rr.y & 0xffff)) + er4.z;
                float l3 = b2f((ushort_t)((uint_t)rr.y >> 16))    + er4.w;
                l0 = (l0 > 0.f) ? l0 : 0.2f * l0;
                l1 = (l1 > 0.f) ? l1 : 0.2f * l1;
                l2 = (l2 > 0.f) ? l2 : 0.2f * l2;
                l3 = (l3 > 0.f) ? l3 : 0.2f * l3;
                a0 = __expf(l0); a1 = __expf(l1); a2 = __expf(l2); a3 = __expf(l3);
                sn = rr.z; eid = rr.w;
            }
        }
        z0 += a0; z1 += a1; z2 += a2; z3 += a3;
        ushort4 nv = *(const ushort4*)&nb[(size_t)sn*64 + li*4];
        float nd0 = b2f(nv.x), nd1 = b2f(nv.y), nd2 = b2f(nv.z), nd3 = b2f(nv.w);
        t[0][0] = fmaf(a0, nd0, t[0][0]); t[0][1] = fmaf(a0, nd1, t[0][1]);
        t[0][2] = fmaf(a0, nd2, t[0][2]); t[0][3] = fmaf(a0, nd3, t[0][3]);
        t[1][0] = fmaf(a1, nd0, t[1][0]); t[1][1] = fmaf(a1, nd1, t[1][1]);
        t[1][2] = fmaf(a1, nd2, t[1][2]); t[1][3] = fmaf(a1, nd3, t[1][3]);
        t[2][0] = fmaf(a2, nd0, t[2][0]); t[2][1] = fmaf(a2, nd1, t[2][1]);
        t[2][2] = fmaf(a2, nd2, t[2][2]); t[2][3] = fmaf(a2, nd3, t[2][3]);
        t[3][0] = fmaf(a3, nd0, t[3][0]); t[3][1] = fmaf(a3, nd1, t[3][1]);
        t[3][2] = fmaf(a3, nd2, t[3][2]); t[3][3] = fmaf(a3, nd3, t[3][3]);
        float efv = edge_feat[(size_t)eid*16 + li];
        q[0] = fmaf(a0, efv, q[0]);
        q[1] = fmaf(a1, efv, q[1]);
        q[2] = fmaf(a2, efv, q[2]);
        q[3] = fmaf(a3, efv, q[3]);
    }

    float zinv[4];
    zinv[0] = (z0 > 0.f) ? 1.f / z0 : 0.f;
    zinv[1] = (z1 > 0.f) ? 1.f / z1 : 0.f;
    zinv[2] = (z2 > 0.f) ? 1.f / z2 : 0.f;
    zinv[3] = (z3 > 0.f) ? 1.f / z3 : 0.f;

    ushort_t* up = u + (size_t)node * 320;
#pragma unroll
    for (int h = 0; h < 4; h++) {
        ushort4 tv;
        tv.x = f2b(t[h][0] * zinv[h]); tv.y = f2b(t[h][1] * zinv[h]);
        tv.z = f2b(t[h][2] * zinv[h]); tv.w = f2b(t[h][3] * zinv[h]);
        *(ushort4*)&up[h*64 + li*4] = tv;
        up[256 + h*16 + li] = f2b(q[h] * zinv[h]);
    }
}

// MFMA conv v4: wave per 2 tiles (32 rows); ALL A prefetched; cb-outer with
// b[10] batch-prefetch (only one acc pair live). No barriers, no LDS.
__global__ __launch_bounds__(256) void conv_kernel(
    const ushort_t* __restrict__ u, const ushort_t* __restrict__ wcvt,
    const float* __restrict__ Cb, const float* __restrict__ convb2,
    const int* __restrict__ offs, ushort_t* __restrict__ rst, float* __restrict__ scr)
{
    int tid = threadIdx.x, lane = tid & 63;
    int li = lane & 15, lg = lane >> 4;
    int widx = blockIdx.x * 4 + (tid >> 6);
    if (widx >= N_CWAVES) return;
    int tile0 = widx * 2, tile1 = widx * 2 + 1;
    bool t1ok = tile1 < N_TILES;
    int n0 = tile0 * 16;
    int n1 = t1ok ? tile1 * 16 : n0;

    short8_t a0[10], a1[10];
    const ushort_t* urow0 = u + (size_t)(n0 + li) * 320 + lg * 8;
    const ushort_t* urow1 = u + (size_t)(n1 + li) * 320 + lg * 8;
#pragma unroll
    for (int kt = 0; kt < 10; kt++) {
        a0[kt] = *(const short8_t*)(urow0 + kt * 32);
        a1[kt] = *(const short8_t*)(urow1 + kt * 32);
    }

    float fl0[4], fl1[4];
#pragma unroll
    for (int j = 0; j < 4; j++) {
        int na = n0 + lg*4 + j;
        int nbb = n1 + lg*4 + j;
        fl0[j] = (offs[na+1] > offs[na]) ? 1.f : 0.f;
        fl1[j] = (offs[nbb+1] > offs[nbb]) ? 1.f : 0.f;
    }

    const ushort_t* wbase = wcvt + ((size_t)lg * 256 + li) * 8;
    float ds[4] = {0.f, 0.f, 0.f, 0.f};
    float dsq[4] = {0.f, 0.f, 0.f, 0.f};

#pragma unroll 2
    for (int cb = 0; cb < 16; cb++) {
        short8_t b[10];
#pragma unroll
        for (int kt = 0; kt < 10; kt++)
            b[kt] = *(const short8_t*)(wbase + (size_t)kt * 8192 + (size_t)cb * 128);
        f32x4_t acc0 = (f32x4_t){0.f, 0.f, 0.f, 0.f};
        f32x4_t acc1 = (f32x4_t){0.f, 0.f, 0.f, 0.f};
#pragma unroll
        for (int kt = 0; kt < 10; kt++) {
            acc0 = __builtin_amdgcn_mfma_f32_16x16x32_bf16(a0[kt], b[kt], acc0, 0, 0, 0);
            acc1 = __builtin_amdgcn_mfma_f32_16x16x32_bf16(a1[kt], b[kt], acc1, 0, 0, 0);
        }
        int col = cb*16 + li;
        float bias = convb2[col];
        float cbv  = Cb[col];
        float s = 0.f, sq = 0.f;
#pragma unroll
        for (int j = 0; j < 4; j++) {
            float v = acc0[j] + bias + fl0[j] * cbv;
            float r = v / (1.f + __expf(-v));
            rst[(size_t)(n0 + lg*4 + j)*256 + col] = f2b(r);
            s += r; sq += r * r;
        }
        if (t1ok) {
#pragma unroll
            for (int j = 0; j < 4; j++) {
                float v = acc1[j] + bias + fl1[j] * cbv;
                float r = v / (1.f + __expf(-v));
                rst[(size_t)(n1 + lg*4 + j)*256 + col] = f2b(r);
                s += r; sq += r * r;
            }
        }
        s  += __shfl_xor(s, 16, 64);  s  += __shfl_xor(s, 32, 64);
        sq += __shfl_xor(sq, 16, 64); sq += __shfl_xor(sq, 32, 64);
        ds[cb & 3]  += s;
        dsq[cb & 3] += sq;
    }
    if (lg == 0) {
        float* sp = scr + (size_t)widx * 128;
#pragma unroll
        for (int m = 0; m < 4; m++) {
            sp[m*16 + li]      = ds[m];
            sp[64 + m*16 + li] = dsq[m];
        }
    }
}

__global__ __launch_bounds__(128) void scr_reduce_kernel(const float* __restrict__ scr,
                                                         float* __restrict__ scr2)
{
    int b = blockIdx.x, tid = threadIdx.x;
    float s = 0.f;
    for (int r = b; r < N_CWAVES; r += 128) s += scr[(size_t)r*128 + tid];
    scr2[(size_t)b*128 + tid] = s;
}

__global__ void bn_finalize_kernel(const float* __restrict__ scr2, const float* __restrict__ gamma2,
                                   const float* __restrict__ beta2, float* __restrict__ ss)
{
    __shared__ float part[8][128];
    __shared__ float tot[128];
    int j = threadIdx.x & 127, chunk = threadIdx.x >> 7;
    float t = 0.f;
    for (int b = chunk; b < 128; b += 8) t += scr2[(size_t)b*128 + j];
    part[chunk][j] = t;
    __syncthreads();
    if (threadIdx.x < 128) {
        float sgm = 0.f;
        for (int c = 0; c < 8; c++) sgm += part[c][threadIdx.x];
        tot[threadIdx.x] = sgm;
    }
    __syncthreads();
    if (threadIdx.x < 64) {
        float inv = 1.f / (float)(N_NODES * HEADS);
        float mean = tot[threadIdx.x] * inv;
        float var  = tot[64 + threadIdx.x] * inv - mean * mean;
        float sc = gamma2[threadIdx.x] * rsqrtf(var + 1e-5f);
        ss[threadIdx.x]      = sc;
        ss[64 + threadIdx.x] = beta2[threadIdx.x] - mean * sc;
    }
}

// blocks 0..63: WhT tiled; block 64: hb2
__global__ void head_prep_kernel(const float* __restrict__ ss, const float* __restrict__ headw,
                                 const float* __restrict__ headb,
                                 ushort_t* __restrict__ wht, float* __restrict__ hb2)
{
    int b = blockIdx.x, tid = threadIdx.x;
    if (b < 64) {
        int idx = b * 256 + tid;                 // 16384 entries
        int c = idx >> 8, k = idx & 255;
        wht[(size_t)((k >> 3)*64 + c)*8 + (k & 7)] = f2b(ss[k & 63] * headw[(size_t)k*64 + c]);
    } else if (tid < 64) {
        float s = headb[tid];
        for (int k = 0; k < 256; k++) s += ss[64 + (k & 63)] * headw[(size_t)k*64 + tid];
        hb2[tid] = s;
    }
}

// MFMA head, LDS-staged B (32KB once): x = rst @ Wh' + hb2
__global__ __launch_bounds__(512) void head_kernel(
    const ushort_t* __restrict__ rst, const ushort_t* __restrict__ wht,
    const float* __restrict__ hb2, float* __restrict__ x)
{
    __shared__ ushort_t Bs[16384];       // [32][64][8] = 32 KB
    int tid = threadIdx.x, w = tid >> 6, lane = tid & 63;
    int li = lane & 15, lg = lane >> 4;
    int tile = blockIdx.x * 8 + w;
    bool active = tile < N_TILES;
    int n0 = tile * 16;

#pragma unroll
    for (int s = 0; s < 4; s++) {
        int i = tid + s*512;
        *(short8_t*)&Bs[(size_t)i*8] = *(const short8_t*)(wht + (size_t)i*8);
    }
    __syncthreads();

    if (!active) return;
    f32x4_t acc[4];
#pragma unroll
    for (int cb = 0; cb < 4; cb++) acc[cb] = (f32x4_t){0.f, 0.f, 0.f, 0.f};
    const ushort_t* rrow = rst + (size_t)(n0 + li) * 256 + lg * 8;
#pragma unroll
    for (int kt = 0; kt < 8; kt++) {
        short8_t a = *(const short8_t*)(rrow + kt * 32);
        short8_t b[4];
#pragma unroll
        for (int cb = 0; cb < 4; cb++)
            b[cb] = *(const short8_t*)&Bs[(size_t)((kt*4 + lg)*64 + cb*16 + li)*8];
#pragma unroll
        for (int cb = 0; cb < 4; cb++)
            acc[cb] = __builtin_amdgcn_mfma_f32_16x16x32_bf16(a, b[cb], acc[cb], 0, 0, 0);
    }
#pragma unroll
    for (int cb = 0; cb < 4; cb++) {
        int col = cb*16 + li;
        float hb = hb2[col];
#pragma unroll
        for (int j = 0; j < 4; j++)
            x[(size_t)(n0 + lg*4 + j)*64 + col] = acc[cb][j] + hb;
    }
}

__global__ __launch_bounds__(1024) void pool_kernel(const float* __restrict__ x,
                                                    const int* __restrict__ gstart,
                                                    float* __restrict__ out)
{
    __shared__ float red[16][64];
    int g = blockIdx.x;
    int lane = threadIdx.x & 63, w = threadIdx.x >> 6;
    int s = gstart[g], e = gstart[g + 1];
    float acc = 0.f;
    for (int n = s + w; n < e; n += 16) acc += x[(size_t)n*64 + lane];
    red[w][lane] = acc;
    __syncthreads();
    if (w == 0) {
        float t = 0.f;
#pragma unroll
        for (int k = 0; k < 16; k++) t += red[k][lane];
        float c = (float)(e - s);
        out[(size_t)g*64 + lane] = t / fmaxf(c, 1.f);
    }
}

__global__ void gather_kernel(const float* __restrict__ x, const int* __restrict__ nidx,
                              float* __restrict__ outq)
{
    int i = blockIdx.x * 256 + threadIdx.x;
    if (i < N_QUERY * HID) {
        int q = i >> 6, c = i & 63;
        outq[i] = x[(size_t)nidx[q]*64 + c];
    }
}

extern "C" void kernel_launch(void* const* d_in, const int* in_sizes, int n_in,
                              void* d_out, int out_size, void* d_ws, size_t ws_size,
                              hipStream_t stream)
{
    const float* node_feat   = (const float*)d_in[0];
    const float* edge_feat   = (const float*)d_in[1];
    const float* node_proj_w = (const float*)d_in[2];
    const float* node_proj_b = (const float*)d_in[3];
    const float* edge_proj_w = (const float*)d_in[4];
    const float* edge_proj_b = (const float*)d_in[5];
    const float* fc_w        = (const float*)d_in[6];
    const float* fc_edge_w   = (const float*)d_in[7];
    const float* attn_l      = (const float*)d_in[8];
    const float* attn_r      = (const float*)d_in[9];
    const float* attn_e      = (const float*)d_in[10];
    const float* conv_bias   = (const float*)d_in[11];
    const float* bn_gamma    = (const float*)d_in[12];
    const float* bn_beta     = (const float*)d_in[13];
    const float* head_w      = (const float*)d_in[14];
    const float* head_b      = (const float*)d_in[15];
    const int*   src         = (const int*)d_in[16];
    const int*   dst         = (const int*)d_in[17];
    const int*   gids        = (const int*)d_in[18];
    const int*   nidx        = (const int*)d_in[19];

    if (ws_size < WS_TOTAL * sizeof(float)) return;

    float* ws  = (float*)d_ws;
    float* out = (float*)d_out;

    const int L2 = 2;
    const float* fcw2   = fc_w      + (size_t)L2 * HID * HEADS * HID;
    const float* fcew2  = fc_edge_w + (size_t)L2 * HID * HEADS * HID;
    const float* attl2  = attn_l    + (size_t)L2 * HEADS * HID;
    const float* attr2  = attn_r    + (size_t)L2 * HEADS * HID;
    const float* atte2  = attn_e    + (size_t)L2 * HEADS * HID;
    const float* convb2 = conv_bias + (size_t)L2 * HEADS * HID;
    const float* gamma2 = bn_gamma  + (size_t)L2 * HID;
    const float* beta2  = bn_beta   + (size_t)L2 * HID;

    int*   deg     = (int*)(ws + OFF_DEG);
    int*   gstart  = (int*)(ws + OFF_GST);
    int*   offs    = (int*)(ws + OFF_OFFS);
    int*   rank    = (int*)(ws + OFF_RANK);
    float* Al      = ws + OFF_AL;
    float* Ar      = ws + OFF_AR;
    float* Bm      = ws + OFF_B;
    float* Ce      = ws + OFF_CE;
    float* Cb      = ws + OFF_CB;
    float* ss      = ws + OFF_SS;
    float* hb2     = ws + OFF_HB2;
    float* Wqe     = ws + OFF_WQE;
    ushort_t* wcvt = (ushort_t*)(ws + OFF_WCVT);
    ushort_t* wht  = (ushort_t*)(ws + OFF_WHT);
    float* el      = ws + OFF_EL;
    float* er      = ws + OFF_ER;
    ushort_t* nb   = (ushort_t*)(ws + OFF_NB);
    int4*  rec     = (int4*)(ws + OFF_REC);
    ushort_t* u    = (ushort_t*)(ws + OFF_U);
    ushort_t* rst  = (ushort_t*)(ws + OFF_RST);
    float* x       = ws + OFF_X;
    float* scr     = ws + OFF_SCR;
    float* scr2    = ws + OFF_SCR2;
    int*   bsum    = (int*)(ws + OFF_BSUM);

    hipMemsetAsync(d_ws, 0, N_NODES * sizeof(int), stream);   // deg = 0

    setup1_kernel<<<18, 256, 0, stream>>>(fcw2, fcew2, attl2, attr2, atte2,
                                          edge_proj_w, edge_proj_b, gids,
                                          Al, Ar, Bm, Ce, Cb, Wqe, gstart);
    wcvt_kernel<<<40, 256, 0, stream>>>(fcw2, Wqe, wcvt);
    node_proj_kernel<<<N_NODES/4, 256, 0, stream>>>(node_feat, node_proj_w, node_proj_b,
                                                    Al, Ar, nb, el, er);
    hist_kernel<<<(N_EDGES + 255)/256, 256, 0, stream>>>(dst, deg, rank);
    scan1_kernel<<<N_SBLK, 1024, 0, stream>>>(deg, offs, bsum);
    scan2_kernel<<<1, 64, 0, stream>>>(bsum, offs);
    scan3_kernel<<<N_SBLK, 1024, 0, stream>>>(offs, bsum);
    logit_kernel<<<(N_EDGES + 255)/256, 256, 0, stream>>>(rank, offs, src, dst, edge_feat,
                                                          el, Bm, Ce, rec);
    accum_kernel<<<N_NODES/16, 256, 0, stream>>>(offs, rec, er, edge_feat, nb, u);
    conv_kernel<<<N_CBLK, 256, 0, stream>>>(u, wcvt, Cb, convb2, offs, rst, scr);
    scr_reduce_kernel<<<128, 128, 0, stream>>>(scr, scr2);
    bn_finalize_kernel<<<1, 1024, 0, stream>>>(scr2, gamma2, beta2, ss);
    head_prep_kernel<<<65, 256, 0, stream>>>(ss, head_w, head_b, wht, hb2);
    head_kernel<<<(N_TILES + 7)/8, 512, 0, stream>>>(rst, wht, hb2, x);
    pool_kernel<<<N_GRAPHS, 1024, 0, stream>>>(x, gstart, out);
    gather_kernel<<<(N_QUERY*HID + 255)/256, 256, 0, stream>>>(x, nidx, out + N_GRAPHS*HID);
}

// Round 15
// 243.353 us; speedup vs baseline: 1.2378x; 1.0387x over previous
//
#include <hip/hip_runtime.h>
#include <cstdint>
#include <cstddef>

#define N_NODES 50000
#define N_EDGES 800000
#define HID 64
#define HEADS 4
#define N_GRAPHS 32
#define N_QUERY 4096
#define N_TILES 3125        // 50000 / 16
#define N_CWAVES 1563       // ceil(3125/2), 2 tiles per wave
#define N_CBLK 391          // ceil(1563/4)
#define N_SBLK 49           // ceil(50000/1024)
#define N_PBLK 782          // ceil(3125/4) node_proj blocks

typedef unsigned short ushort_t;
typedef unsigned int uint_t;
typedef __attribute__((ext_vector_type(8))) short short8_t;
typedef __attribute__((ext_vector_type(4))) float f32x4_t;

__device__ __forceinline__ float b2f(ushort_t h) { return __uint_as_float(((uint_t)h) << 16); }
__device__ __forceinline__ ushort_t f2b(float f) {
    uint_t u = __float_as_uint(f);
    uint_t r = (u + 0x7FFFu + ((u >> 16) & 1u)) >> 16;
    return (ushort_t)r;
}

// ---- workspace layout (4-byte element offsets) ----
static constexpr size_t OFF_DEG   = 0;          // int[50000]
static constexpr size_t OFF_GST   = 50016;      // int[33]
static constexpr size_t OFF_OFFS  = 50064;      // int[50001]
static constexpr size_t OFF_RANK  = 100080;     // int[800000]
static constexpr size_t OFF_AL    = 900080;     // float[256]
static constexpr size_t OFF_AR    = 900336;     // float[256]
static constexpr size_t OFF_B     = 900592;     // float[64]
static constexpr size_t OFF_CE    = 900656;     // float[16]
static constexpr size_t OFF_CB    = 900672;     // float[256]
static constexpr size_t OFF_SS    = 900928;     // float[128]
static constexpr size_t OFF_HB2   = 901056;     // float[64]
static constexpr size_t OFF_WQE   = 901120;     // float[4096]
static constexpr size_t OFF_WCVT  = 905216;     // bf16 tiled [40][256][8] -> 40960 float slots
static constexpr size_t OFF_WHT   = 946176;     // bf16 tiled [32][64][8]  -> 8192 float slots
static constexpr size_t OFF_EL    = 954368;     // float[200000]
static constexpr size_t OFF_ER    = 1154368;    // float[200000]
static constexpr size_t OFF_NB    = 1354368;    // bf16[50000*64] -> 1.6M float slots
static constexpr size_t OFF_REC   = 2954368;    // 16B records: int4[800064] -> 3200256 slots
static constexpr size_t OFF_U     = 6154624;    // bf16[50000*320] -> 8M float slots
static constexpr size_t OFF_RST   = 14154624;   // bf16[50000*256] -> 6.4M float slots
static constexpr size_t OFF_X     = 20554624;   // float[3200000]
static constexpr size_t OFF_SCR   = 23754624;   // float[1563*128]
static constexpr size_t OFF_SCR2  = 24154624;   // float[16384]
static constexpr size_t OFF_BSUM  = 24171008;   // int[64]
static constexpr size_t OFF_WPB   = 24171072;   // bf16 tiled [2][4][4][16][8] -> 2048 float slots
static constexpr size_t WS_TOTAL  = 24173120;   // elements (~96.7 MB)

// block 0: small algebra; blocks 1..16: Wqe; block 17: bounds; block 18: WpB tiled
__global__ void setup1_kernel(const float* __restrict__ fcw2, const float* __restrict__ fcew2,
                              const float* __restrict__ attl2, const float* __restrict__ attr2,
                              const float* __restrict__ atte2,
                              const float* __restrict__ wpe, const float* __restrict__ bpe,
                              const float* __restrict__ wpn, const int* __restrict__ gids,
                              float* __restrict__ Al, float* __restrict__ Ar,
                              float* __restrict__ B, float* __restrict__ Ce,
                              float* __restrict__ Cb, float* __restrict__ Wqe,
                              int* __restrict__ gstart, ushort_t* __restrict__ wpb)
{
    int b = blockIdx.x, tid = threadIdx.x;
    if (b == 0) {
        __shared__ float AE[256];
        int c = tid >> 2, h = tid & 3;
        float al = 0.f, ar = 0.f, ae = 0.f;
        for (int d = 0; d < 64; d++) {
            float wl = fcw2[c*256 + h*64 + d];
            float we = fcew2[c*256 + h*64 + d];
            al = fmaf(wl, attl2[h*64 + d], al);
            ar = fmaf(wl, attr2[h*64 + d], ar);
            ae = fmaf(we, atte2[h*64 + d], ae);
        }
        Al[c*4 + h] = al;
        Ar[c*4 + h] = ar;
        AE[c*4 + h] = ae;
        __syncthreads();
        if (tid < 64) {
            int kk = tid >> 2, hh = tid & 3;
            float bb = 0.f;
            for (int d = 0; d < 64; d++) bb = fmaf(wpe[kk*64 + d], AE[d*4 + hh], bb);
            B[kk*4 + hh] = bb;
        }
        if (tid < 4) {
            float ce = 0.f;
            for (int d = 0; d < 64; d++) ce = fmaf(bpe[d], AE[d*4 + tid], ce);
            Ce[tid] = ce;
        }
        {
            float cb = 0.f;
            for (int d = 0; d < 64; d++) cb = fmaf(bpe[d], fcew2[d*256 + tid], cb);
            Cb[tid] = cb;
        }
    } else if (b <= 16) {
        int idx = (b - 1) * 256 + tid;           // 4096
        int hh = idx >> 10, rem = idx & 1023, kk = rem >> 6, cc = rem & 63;
        float w = 0.f;
        for (int d = 0; d < 64; d++) w = fmaf(wpe[kk*64 + d], fcew2[d*256 + hh*64 + cc], w);
        Wqe[idx] = w;
    } else if (b == 17) {
        int g = tid;
        if (g <= N_GRAPHS) {
            int lo = 0, hi = N_NODES;
            while (lo < hi) { int mid = (lo + hi) >> 1; if (gids[mid] < g) lo = mid + 1; else hi = mid; }
            gstart[g] = lo;
        }
    } else {
        // WpB tiled: g in [0,512): kt=g>>8, lg=(g>>6)&3, cb=(g>>4)&3, li=g&15
        for (int s = 0; s < 2; s++) {
            int g = tid + s*256;
            int kt = g >> 8, lg = (g >> 6) & 3, cb = (g >> 4) & 3, li = g & 15;
            short8_t v;
#pragma unroll
            for (int j = 0; j < 8; j++)
                v[j] = (short)f2b(wpn[(size_t)(kt*32 + lg*8 + j)*64 + cb*16 + li]);
            *(short8_t*)&wpb[(size_t)g*8] = v;
        }
    }
}

// WcvT tiled builder: thread per (kt,col), writes contiguous short8 (40 blocks)
__global__ void wcvt_kernel(const float* __restrict__ fcw2, const float* __restrict__ Wqe,
                            ushort_t* __restrict__ wcvt)
{
    int idx = blockIdx.x * 256 + threadIdx.x;    // 10240 = 40*256
    int kt = idx >> 8, col = idx & 255;
    int hc = col >> 6;
    short8_t v8;
#pragma unroll
    for (int j = 0; j < 8; j++) {
        int k = kt*8 + j;
        float v;
        if (k < 256) {
            v = ((k >> 6) == hc) ? fcw2[(size_t)(k & 63)*256 + col] : 0.f;
        } else {
            int kq = k - 256, hh = kq >> 4;
            v = (hh == hc) ? Wqe[hh*1024 + (kq & 15)*64 + (col & 63)] : 0.f;
        }
        v8[j] = (short)f2b(v);
    }
    *(short8_t*)&wcvt[(size_t)idx*8] = v8;
}

// MFMA node_proj: wave per 16-node tile. A built from f32 nf (inline bf16 pack),
// B = 2KB tiled WpB (L1). Epilogue: bias, nb store, el/er via lane-reduce.
__global__ __launch_bounds__(256) void node_proj_kernel(
    const float* __restrict__ nf, const ushort_t* __restrict__ wpb,
    const float* __restrict__ bpn, const float* __restrict__ Al, const float* __restrict__ Ar,
    ushort_t* __restrict__ nb, float* __restrict__ el, float* __restrict__ er)
{
    int tid = threadIdx.x, lane = tid & 63;
    int li = lane & 15, lg = lane >> 4;
    int tile = blockIdx.x * 4 + (tid >> 6);
    if (tile >= N_TILES) return;
    int n0 = tile * 16;

    short8_t a[2];
#pragma unroll
    for (int kt = 0; kt < 2; kt++) {
        const float* ap = nf + (size_t)(n0 + li) * 64 + kt*32 + lg*8;
        float4 f0 = *(const float4*)ap;
        float4 f1 = *(const float4*)(ap + 4);
        short8_t v;
        v[0] = (short)f2b(f0.x); v[1] = (short)f2b(f0.y);
        v[2] = (short)f2b(f0.z); v[3] = (short)f2b(f0.w);
        v[4] = (short)f2b(f1.x); v[5] = (short)f2b(f1.y);
        v[6] = (short)f2b(f1.z); v[7] = (short)f2b(f1.w);
        a[kt] = v;
    }

    f32x4_t acc[4];
#pragma unroll
    for (int cb = 0; cb < 4; cb++) acc[cb] = (f32x4_t){0.f, 0.f, 0.f, 0.f};
#pragma unroll
    for (int kt = 0; kt < 2; kt++) {
#pragma unroll
        for (int cb = 0; cb < 4; cb++) {
            short8_t b = *(const short8_t*)&wpb[(size_t)((((kt*4 + lg)*4 + cb)*16) + li)*8];
            acc[cb] = __builtin_amdgcn_mfma_f32_16x16x32_bf16(a[kt], b, acc[cb], 0, 0, 0);
        }
    }

    float pl[4][4] = {{0.f}}, pr[4][4] = {{0.f}};
#pragma unroll
    for (int cb = 0; cb < 4; cb++) {
        int c = cb*16 + li;
        float bias = bpn[c];
#pragma unroll
        for (int j = 0; j < 4; j++) {
            float val = acc[cb][j] + bias;
            nb[(size_t)(n0 + lg*4 + j)*64 + c] = f2b(val);
#pragma unroll
            for (int h = 0; h < 4; h++) {
                pl[j][h] = fmaf(val, Al[c*4 + h], pl[j][h]);
                pr[j][h] = fmaf(val, Ar[c*4 + h], pr[j][h]);
            }
        }
    }
#pragma unroll
    for (int off = 1; off < 16; off <<= 1) {
#pragma unroll
        for (int j = 0; j < 4; j++)
#pragma unroll
            for (int h = 0; h < 4; h++) {
                pl[j][h] += __shfl_xor(pl[j][h], off, 64);
                pr[j][h] += __shfl_xor(pr[j][h], off, 64);
            }
    }
    if (li < 4) {
        int h = li;
#pragma unroll
        for (int j = 0; j < 4; j++) {
            int n = n0 + lg*4 + j;
            el[(size_t)n*4 + h] = pl[j][h];
            er[(size_t)n*4 + h] = pr[j][h];
        }
    }
}

// deg histogram + per-edge rank within its dst bucket
__global__ void hist_kernel(const int* __restrict__ dst, int* __restrict__ deg,
                            int* __restrict__ rank)
{
    int e = blockIdx.x * 256 + threadIdx.x;
    if (e < N_EDGES) rank[e] = atomicAdd(&deg[dst[e]], 1);
}

// multi-block scan phase 1: block-local exclusive scan + block sums (49 blocks)
__global__ __launch_bounds__(1024) void scan1_kernel(const int* __restrict__ deg,
                                                     int* __restrict__ offs,
                                                     int* __restrict__ bsum)
{
    __shared__ int wsum[16];
    int b = blockIdx.x, tid = threadIdx.x, lane = tid & 63, w = tid >> 6;
    int i = b * 1024 + tid;
    int v = (i < N_NODES) ? deg[i] : 0;
    int incl = v;
#pragma unroll
    for (int off = 1; off < 64; off <<= 1) {
        int y = __shfl_up(incl, off, 64);
        if (lane >= off) incl += y;
    }
    if (lane == 63) wsum[w] = incl;
    __syncthreads();
    int woff = 0;
#pragma unroll
    for (int k = 0; k < 15; k++) woff += (k < w) ? wsum[k] : 0;
    if (i < N_NODES) offs[i] = woff + incl - v;
    if (tid == 1023) bsum[b] = woff + incl;
}

// phase 2: one wave scans the 49 block sums -> exclusive bases, writes total
__global__ void scan2_kernel(int* __restrict__ bsum, int* __restrict__ offs)
{
    int tid = threadIdx.x;  // 64
    int v = (tid < N_SBLK) ? bsum[tid] : 0;
    int incl = v;
#pragma unroll
    for (int off = 1; off < 64; off <<= 1) {
        int y = __shfl_up(incl, off, 64);
        if (tid >= off) incl += y;
    }
    if (tid < N_SBLK) bsum[tid] = incl - v;
    if (tid == N_SBLK - 1) offs[N_NODES] = incl;
}

// phase 3: add block bases (49 blocks)
__global__ __launch_bounds__(1024) void scan3_kernel(int* __restrict__ offs,
                                                     const int* __restrict__ bsum)
{
    int i = blockIdx.x * 1024 + threadIdx.x;
    if (i < N_NODES) offs[i] += bsum[blockIdx.x];
}

// 1 edge/thread. 16B record per edge: {l4 bf16x4 (pre-leaky, no er), src, eid}.
__global__ __launch_bounds__(256) void logit_kernel(
    const int* __restrict__ rank, const int* __restrict__ offs,
    const int* __restrict__ src, const int* __restrict__ dst,
    const float* __restrict__ edge_feat, const float* __restrict__ el,
    const float* __restrict__ B, const float* __restrict__ Ce,
    int4* __restrict__ rec)
{
    int e = blockIdx.x * 256 + threadIdx.x;
    if (e >= N_EDGES) return;
    int sn = src[e], dn = dst[e];
    const float4* el4 = (const float4*)el;
    float4 a = el4[sn];
    float l0 = Ce[0] + a.x;
    float l1 = Ce[1] + a.y;
    float l2 = Ce[2] + a.z;
    float l3 = Ce[3] + a.w;
    const float4* ef4 = (const float4*)(edge_feat + (size_t)e * 16);
    float4 e0 = ef4[0], e1 = ef4[1], e2 = ef4[2], e3 = ef4[3];
    float ef[16] = {e0.x,e0.y,e0.z,e0.w, e1.x,e1.y,e1.z,e1.w,
                    e2.x,e2.y,e2.z,e2.w, e3.x,e3.y,e3.z,e3.w};
#pragma unroll
    for (int k = 0; k < 16; k++) {
        float f = ef[k];
        l0 = fmaf(f, B[k*4 + 0], l0);
        l1 = fmaf(f, B[k*4 + 1], l1);
        l2 = fmaf(f, B[k*4 + 2], l2);
        l3 = fmaf(f, B[k*4 + 3], l3);
    }
    int slot = offs[dn] + rank[e];
    uint_t lo01 = (uint_t)f2b(l0) | ((uint_t)f2b(l1) << 16);
    uint_t lo23 = (uint_t)f2b(l2) | ((uint_t)f2b(l3) << 16);
    rec[slot] = make_int4((int)lo01, (int)lo23, sn, e);
}

// 16-lane group per node, 4 nodes/wave; er+leaky+exp here; one-pass softmax
__global__ __launch_bounds__(256) void accum_kernel(
    const int* __restrict__ offs, const int4* __restrict__ rec,
    const float* __restrict__ er, const float* __restrict__ edge_feat,
    const ushort_t* __restrict__ nb, ushort_t* __restrict__ u)
{
    int tid = threadIdx.x;
    int lane = tid & 63;
    int li = lane & 15;
    int node = blockIdx.x * 16 + (tid >> 6) * 4 + ((lane >> 4) & 3);
    int start = offs[node], end = offs[node + 1];
    int deg = end - start;

    float4 er4 = *(const float4*)&er[(size_t)node*4];
    const int4 Z4 = make_int4(0, 0, 0, 0);
    int4 r0 = (li < deg)      ? rec[start + li]      : Z4;
    int4 r1 = (16 + li < deg) ? rec[start + 16 + li] : Z4;

    float pe0[4], pe1[4];
    {
        float l[4] = { b2f((ushort_t)((uint_t)r0.x & 0xffff)) + er4.x,
                       b2f((ushort_t)((uint_t)r0.x >> 16))    + er4.y,
                       b2f((ushort_t)((uint_t)r0.y & 0xffff)) + er4.z,
                       b2f((ushort_t)((uint_t)r0.y >> 16))    + er4.w };
#pragma unroll
        for (int h = 0; h < 4; h++) {
            float lv = (l[h] > 0.f) ? l[h] : 0.2f * l[h];
            pe0[h] = (li < deg) ? __expf(lv) : 0.f;
        }
    }
    {
        float l[4] = { b2f((ushort_t)((uint_t)r1.x & 0xffff)) + er4.x,
                       b2f((ushort_t)((uint_t)r1.x >> 16))    + er4.y,
                       b2f((ushort_t)((uint_t)r1.y & 0xffff)) + er4.z,
                       b2f((ushort_t)((uint_t)r1.y >> 16))    + er4.w };
#pragma unroll
        for (int h = 0; h < 4; h++) {
            float lv = (l[h] > 0.f) ? l[h] : 0.2f * l[h];
            pe1[h] = (16 + li < deg) ? __expf(lv) : 0.f;
        }
    }
    int sn0 = r0.z, eid0 = r0.w;
    int sn1 = r1.z, eid1 = r1.w;

    int mdeg = deg;
#pragma unroll
    for (int off = 1; off < 64; off <<= 1) mdeg = max(mdeg, __shfl_xor(mdeg, off, 64));
    mdeg = __builtin_amdgcn_readfirstlane(mdeg);

    float z0 = 0.f, z1 = 0.f, z2 = 0.f, z3 = 0.f;
    float t[4][4] = {{0.f}};
    float q[4] = {0.f, 0.f, 0.f, 0.f};
    int grpbase = lane & 48;

#pragma unroll 2
    for (int j = 0; j < mdeg; ++j) {
        bool act = j < deg;
        float a0, a1, a2, a3;
        int sn, eid;
        if (j < 32) {
            float v0 = (j < 16) ? pe0[0] : pe1[0];
            float v1 = (j < 16) ? pe0[1] : pe1[1];
            float v2 = (j < 16) ? pe0[2] : pe1[2];
            float v3 = (j < 16) ? pe0[3] : pe1[3];
            int vs = (j < 16) ? sn0 : sn1;
            int ve = (j < 16) ? eid0 : eid1;
            int sl = grpbase | (j & 15);
            a0 = __shfl(v0, sl, 64);
            a1 = __shfl(v1, sl, 64);
            a2 = __shfl(v2, sl, 64);
            a3 = __shfl(v3, sl, 64);
            sn  = __shfl(vs, sl, 64);
            eid = __shfl(ve, sl, 64);
        } else {
            a0 = a1 = a2 = a3 = 0.f;
            sn = 0; eid = 0;
            if (act) {
                int4 rr = rec[start + j];
                float l0 = b2f((ushort_t)((uint_t)rr.x & 0xffff)) + er4.x;
                float l1 = b2f((ushort_t)((uint_t)rr.x >> 16))    + er4.y;
                float l2 = b2f((ushort_t)((uint_t)rr.y & 0xffff)) + er4.z;
                float l3 = b2f((ushort_t)((uint_t)rr.y >> 16))    + er4.w;
                l0 = (l0 > 0.f) ? l0 : 0.2f * l0;
                l1 = (l1 > 0.f) ? l1 : 0.2f * l1;
                l2 = (l2 > 0.f) ? l2 : 0.2f * l2;
                l3 = (l3 > 0.f) ? l3 : 0.2f * l3;
                a0 = __expf(l0); a1 = __expf(l1); a2 = __expf(l2); a3 = __expf(l3);
                sn = rr.z; eid = rr.w;
            }
        }
        z0 += a0; z1 += a1; z2 += a2; z3 += a3;
        ushort4 nv = *(const ushort4*)&nb[(size_t)sn*64 + li*4];
        float nd0 = b2f(nv.x), nd1 = b2f(nv.y), nd2 = b2f(nv.z), nd3 = b2f(nv.w);
        t[0][0] = fmaf(a0, nd0, t[0][0]); t[0][1] = fmaf(a0, nd1, t[0][1]);
        t[0][2] = fmaf(a0, nd2, t[0][2]); t[0][3] = fmaf(a0, nd3, t[0][3]);
        t[1][0] = fmaf(a1, nd0, t[1][0]); t[1][1] = fmaf(a1, nd1, t[1][1]);
        t[1][2] = fmaf(a1, nd2, t[1][2]); t[1][3] = fmaf(a1, nd3, t[1][3]);
        t[2][0] = fmaf(a2, nd0, t[2][0]); t[2][1] = fmaf(a2, nd1, t[2][1]);
        t[2][2] = fmaf(a2, nd2, t[2][2]); t[2][3] = fmaf(a2, nd3, t[2][3]);
        t[3][0] = fmaf(a3, nd0, t[3][0]); t[3][1] = fmaf(a3, nd1, t[3][1]);
        t[3][2] = fmaf(a3, nd2, t[3][2]); t[3][3] = fmaf(a3, nd3, t[3][3]);
        float efv = edge_feat[(size_t)eid*16 + li];
        q[0] = fmaf(a0, efv, q[0]);
        q[1] = fmaf(a1, efv, q[1]);
        q[2] = fmaf(a2, efv, q[2]);
        q[3] = fmaf(a3, efv, q[3]);
    }

    float zinv[4];
    zinv[0] = (z0 > 0.f) ? 1.f / z0 : 0.f;
    zinv[1] = (z1 > 0.f) ? 1.f / z1 : 0.f;
    zinv[2] = (z2 > 0.f) ? 1.f / z2 : 0.f;
    zinv[3] = (z3 > 0.f) ? 1.f / z3 : 0.f;

    ushort_t* up = u + (size_t)node * 320;
#pragma unroll
    for (int h = 0; h < 4; h++) {
        ushort4 tv;
        tv.x = f2b(t[h][0] * zinv[h]); tv.y = f2b(t[h][1] * zinv[h]);
        tv.z = f2b(t[h][2] * zinv[h]); tv.w = f2b(t[h][3] * zinv[h]);
        *(ushort4*)&up[h*64 + li*4] = tv;
        up[256 + h*16 + li] = f2b(q[h] * zinv[h]);
    }
}

// MFMA conv v4: wave per 2 tiles (32 rows); ALL A prefetched; cb-outer with
// b[10] batch-prefetch (only one acc pair live). No barriers, no LDS.
__global__ __launch_bounds__(256) void conv_kernel(
    const ushort_t* __restrict__ u, const ushort_t* __restrict__ wcvt,
    const float* __restrict__ Cb, const float* __restrict__ convb2,
    const int* __restrict__ offs, ushort_t* __restrict__ rst, float* __restrict__ scr)
{
    int tid = threadIdx.x, lane = tid & 63;
    int li = lane & 15, lg = lane >> 4;
    int widx = blockIdx.x * 4 + (tid >> 6);
    if (widx >= N_CWAVES) return;
    int tile0 = widx * 2, tile1 = widx * 2 + 1;
    bool t1ok = tile1 < N_TILES;
    int n0 = tile0 * 16;
    int n1 = t1ok ? tile1 * 16 : n0;

    short8_t a0[10], a1[10];
    const ushort_t* urow0 = u + (size_t)(n0 + li) * 320 + lg * 8;
    const ushort_t* urow1 = u + (size_t)(n1 + li) * 320 + lg * 8;
#pragma unroll
    for (int kt = 0; kt < 10; kt++) {
        a0[kt] = *(const short8_t*)(urow0 + kt * 32);
        a1[kt] = *(const short8_t*)(urow1 + kt * 32);
    }

    float fl0[4], fl1[4];
#pragma unroll
    for (int j = 0; j < 4; j++) {
        int na = n0 + lg*4 + j;
        int nbb = n1 + lg*4 + j;
        fl0[j] = (offs[na+1] > offs[na]) ? 1.f : 0.f;
        fl1[j] = (offs[nbb+1] > offs[nbb]) ? 1.f : 0.f;
    }

    const ushort_t* wbase = wcvt + ((size_t)lg * 256 + li) * 8;
    float ds[4] = {0.f, 0.f, 0.f, 0.f};
    float dsq[4] = {0.f, 0.f, 0.f, 0.f};

#pragma unroll 2
    for (int cb = 0; cb < 16; cb++) {
        short8_t b[10];
#pragma unroll
        for (int kt = 0; kt < 10; kt++)
            b[kt] = *(const short8_t*)(wbase + (size_t)kt * 8192 + (size_t)cb * 128);
        f32x4_t acc0 = (f32x4_t){0.f, 0.f, 0.f, 0.f};
        f32x4_t acc1 = (f32x4_t){0.f, 0.f, 0.f, 0.f};
#pragma unroll
        for (int kt = 0; kt < 10; kt++) {
            acc0 = __builtin_amdgcn_mfma_f32_16x16x32_bf16(a0[kt], b[kt], acc0, 0, 0, 0);
            acc1 = __builtin_amdgcn_mfma_f32_16x16x32_bf16(a1[kt], b[kt], acc1, 0, 0, 0);
        }
        int col = cb*16 + li;
        float bias = convb2[col];
        float cbv  = Cb[col];
        float s = 0.f, sq = 0.f;
#pragma unroll
        for (int j = 0; j < 4; j++) {
            float v = acc0[j] + bias + fl0[j] * cbv;
            float r = v / (1.f + __expf(-v));
            rst[(size_t)(n0 + lg*4 + j)*256 + col] = f2b(r);
            s += r; sq += r * r;
        }
        if (t1ok) {
#pragma unroll
            for (int j = 0; j < 4; j++) {
                float v = acc1[j] + bias + fl1[j] * cbv;
                float r = v / (1.f + __expf(-v));
                rst[(size_t)(n1 + lg*4 + j)*256 + col] = f2b(r);
                s += r; sq += r * r;
            }
        }
        s  += __shfl_xor(s, 16, 64);  s  += __shfl_xor(s, 32, 64);
        sq += __shfl_xor(sq, 16, 64); sq += __shfl_xor(sq, 32, 64);
        ds[cb & 3]  += s;
        dsq[cb & 3] += sq;
    }
    if (lg == 0) {
        float* sp = scr + (size_t)widx * 128;
#pragma unroll
        for (int m = 0; m < 4; m++) {
            sp[m*16 + li]      = ds[m];
            sp[64 + m*16 + li] = dsq[m];
        }
    }
}

__global__ __launch_bounds__(128) void scr_reduce_kernel(const float* __restrict__ scr,
                                                         float* __restrict__ scr2)
{
    int b = blockIdx.x, tid = threadIdx.x;
    float s = 0.f;
    for (int r = b; r < N_CWAVES; r += 128) s += scr[(size_t)r*128 + tid];
    scr2[(size_t)b*128 + tid] = s;
}

__global__ void bn_finalize_kernel(const float* __restrict__ scr2, const float* __restrict__ gamma2,
                                   const float* __restrict__ beta2, float* __restrict__ ss)
{
    __shared__ float part[8][128];
    __shared__ float tot[128];
    int j = threadIdx.x & 127, chunk = threadIdx.x >> 7;
    float t = 0.f;
    for (int b = chunk; b < 128; b += 8) t += scr2[(size_t)b*128 + j];
    part[chunk][j] = t;
    __syncthreads();
    if (threadIdx.x < 128) {
        float sgm = 0.f;
        for (int c = 0; c < 8; c++) sgm += part[c][threadIdx.x];
        tot[threadIdx.x] = sgm;
    }
    __syncthreads();
    if (threadIdx.x < 64) {
        float inv = 1.f / (float)(N_NODES * HEADS);
        float mean = tot[threadIdx.x] * inv;
        float var  = tot[64 + threadIdx.x] * inv - mean * mean;
        float sc = gamma2[threadIdx.x] * rsqrtf(var + 1e-5f);
        ss[threadIdx.x]      = sc;
        ss[64 + threadIdx.x] = beta2[threadIdx.x] - mean * sc;
    }
}

// blocks 0..63: WhT tiled; block 64: hb2
__global__ void head_prep_kernel(const float* __restrict__ ss, const float* __restrict__ headw,
                                 const float* __restrict__ headb,
                                 ushort_t* __restrict__ wht, float* __restrict__ hb2)
{
    int b = blockIdx.x, tid = threadIdx.x;
    if (b < 64) {
        int idx = b * 256 + tid;                 // 16384 entries
        int c = idx >> 8, k = idx & 255;
        wht[(size_t)((k >> 3)*64 + c)*8 + (k & 7)] = f2b(ss[k & 63] * headw[(size_t)k*64 + c]);
    } else if (tid < 64) {
        float s = headb[tid];
        for (int k = 0; k < 256; k++) s += ss[64 + (k & 63)] * headw[(size_t)k*64 + tid];
        hb2[tid] = s;
    }
}

// MFMA head, LDS-staged B (32KB once): x = rst @ Wh' + hb2
__global__ __launch_bounds__(512) void head_kernel(
    const ushort_t* __restrict__ rst, const ushort_t* __restrict__ wht,
    const float* __restrict__ hb2, float* __restrict__ x)
{
    __shared__ ushort_t Bs[16384];       // [32][64][8] = 32 KB
    int tid = threadIdx.x, w = tid >> 6, lane = tid & 63;
    int li = lane & 15, lg = lane >> 4;
    int tile = blockIdx.x * 8 + w;
    bool active = tile < N_TILES;
    int n0 = tile * 16;

#pragma unroll
    for (int s = 0; s < 4; s++) {
        int i = tid + s*512;
        *(short8_t*)&Bs[(size_t)i*8] = *(const short8_t*)(wht + (size_t)i*8);
    }
    __syncthreads();

    if (!active) return;
    f32x4_t acc[4];
#pragma unroll
    for (int cb = 0; cb < 4; cb++) acc[cb] = (f32x4_t){0.f, 0.f, 0.f, 0.f};
    const ushort_t* rrow = rst + (size_t)(n0 + li) * 256 + lg * 8;
#pragma unroll
    for (int kt = 0; kt < 8; kt++) {
        short8_t a = *(const short8_t*)(rrow + kt * 32);
        short8_t b[4];
#pragma unroll
        for (int cb = 0; cb < 4; cb++)
            b[cb] = *(const short8_t*)&Bs[(size_t)((kt*4 + lg)*64 + cb*16 + li)*8];
#pragma unroll
        for (int cb = 0; cb < 4; cb++)
            acc[cb] = __builtin_amdgcn_mfma_f32_16x16x32_bf16(a, b[cb], acc[cb], 0, 0, 0);
    }
#pragma unroll
    for (int cb = 0; cb < 4; cb++) {
        int col = cb*16 + li;
        float hb = hb2[col];
#pragma unroll
        for (int j = 0; j < 4; j++)
            x[(size_t)(n0 + lg*4 + j)*64 + col] = acc[cb][j] + hb;
    }
}

__global__ __launch_bounds__(1024) void pool_kernel(const float* __restrict__ x,
                                                    const int* __restrict__ gstart,
                                                    float* __restrict__ out)
{
    __shared__ float red[16][64];
    int g = blockIdx.x;
    int lane = threadIdx.x & 63, w = threadIdx.x >> 6;
    int s = gstart[g], e = gstart[g + 1];
    float acc = 0.f;
    for (int n = s + w; n < e; n += 16) acc += x[(size_t)n*64 + lane];
    red[w][lane] = acc;
    __syncthreads();
    if (w == 0) {
        float t = 0.f;
#pragma unroll
        for (int k = 0; k < 16; k++) t += red[k][lane];
        float c = (float)(e - s);
        out[(size_t)g*64 + lane] = t / fmaxf(c, 1.f);
    }
}

__global__ void gather_kernel(const float* __restrict__ x, const int* __restrict__ nidx,
                              float* __restrict__ outq)
{
    int i = blockIdx.x * 256 + threadIdx.x;
    if (i < N_QUERY * HID) {
        int q = i >> 6, c = i & 63;
        outq[i] = x[(size_t)nidx[q]*64 + c];
    }
}

extern "C" void kernel_launch(void* const* d_in, const int* in_sizes, int n_in,
                              void* d_out, int out_size, void* d_ws, size_t ws_size,
                              hipStream_t stream)
{
    const float* node_feat   = (const float*)d_in[0];
    const float* edge_feat   = (const float*)d_in[1];
    const float* node_proj_w = (const float*)d_in[2];
    const float* node_proj_b = (const float*)d_in[3];
    const float* edge_proj_w = (const float*)d_in[4];
    const float* edge_proj_b = (const float*)d_in[5];
    const float* fc_w        = (const float*)d_in[6];
    const float* fc_edge_w   = (const float*)d_in[7];
    const float* attn_l      = (const float*)d_in[8];
    const float* attn_r      = (const float*)d_in[9];
    const float* attn_e      = (const float*)d_in[10];
    const float* conv_bias   = (const float*)d_in[11];
    const float* bn_gamma    = (const float*)d_in[12];
    const float* bn_beta     = (const float*)d_in[13];
    const float* head_w      = (const float*)d_in[14];
    const float* head_b      = (const float*)d_in[15];
    const int*   src         = (const int*)d_in[16];
    const int*   dst         = (const int*)d_in[17];
    const int*   gids        = (const int*)d_in[18];
    const int*   nidx        = (const int*)d_in[19];

    if (ws_size < WS_TOTAL * sizeof(float)) return;

    float* ws  = (float*)d_ws;
    float* out = (float*)d_out;

    const int L2 = 2;
    const float* fcw2   = fc_w      + (size_t)L2 * HID * HEADS * HID;
    const float* fcew2  = fc_edge_w + (size_t)L2 * HID * HEADS * HID;
    const float* attl2  = attn_l    + (size_t)L2 * HEADS * HID;
    const float* attr2  = attn_r    + (size_t)L2 * HEADS * HID;
    const float* atte2  = attn_e    + (size_t)L2 * HEADS * HID;
    const float* convb2 = conv_bias + (size_t)L2 * HEADS * HID;
    const float* gamma2 = bn_gamma  + (size_t)L2 * HID;
    const float* beta2  = bn_beta   + (size_t)L2 * HID;

    int*   deg     = (int*)(ws + OFF_DEG);
    int*   gstart  = (int*)(ws + OFF_GST);
    int*   offs    = (int*)(ws + OFF_OFFS);
    int*   rank    = (int*)(ws + OFF_RANK);
    float* Al      = ws + OFF_AL;
    float* Ar      = ws + OFF_AR;
    float* Bm      = ws + OFF_B;
    float* Ce      = ws + OFF_CE;
    float* Cb      = ws + OFF_CB;
    float* ss      = ws + OFF_SS;
    float* hb2     = ws + OFF_HB2;
    float* Wqe     = ws + OFF_WQE;
    ushort_t* wcvt = (ushort_t*)(ws + OFF_WCVT);
    ushort_t* wht  = (ushort_t*)(ws + OFF_WHT);
    float* el      = ws + OFF_EL;
    float* er      = ws + OFF_ER;
    ushort_t* nb   = (ushort_t*)(ws + OFF_NB);
    int4*  rec     = (int4*)(ws + OFF_REC);
    ushort_t* u    = (ushort_t*)(ws + OFF_U);
    ushort_t* rst  = (ushort_t*)(ws + OFF_RST);
    float* x       = ws + OFF_X;
    float* scr     = ws + OFF_SCR;
    float* scr2    = ws + OFF_SCR2;
    int*   bsum    = (int*)(ws + OFF_BSUM);
    ushort_t* wpb  = (ushort_t*)(ws + OFF_WPB);

    hipMemsetAsync(d_ws, 0, N_NODES * sizeof(int), stream);   // deg = 0

    setup1_kernel<<<19, 256, 0, stream>>>(fcw2, fcew2, attl2, attr2, atte2,
                                          edge_proj_w, edge_proj_b, node_proj_w, gids,
                                          Al, Ar, Bm, Ce, Cb, Wqe, gstart, wpb);
    wcvt_kernel<<<40, 256, 0, stream>>>(fcw2, Wqe, wcvt);
    node_proj_kernel<<<N_PBLK, 256, 0, stream>>>(node_feat, wpb, node_proj_b,
                                                 Al, Ar, nb, el, er);
    hist_kernel<<<(N_EDGES + 255)/256, 256, 0, stream>>>(dst, deg, rank);
    scan1_kernel<<<N_SBLK, 1024, 0, stream>>>(deg, offs, bsum);
    scan2_kernel<<<1, 64, 0, stream>>>(bsum, offs);
    scan3_kernel<<<N_SBLK, 1024, 0, stream>>>(offs, bsum);
    logit_kernel<<<(N_EDGES + 255)/256, 256, 0, stream>>>(rank, offs, src, dst, edge_feat,
                                                          el, Bm, Ce, rec);
    accum_kernel<<<N_NODES/16, 256, 0, stream>>>(offs, rec, er, edge_feat, nb, u);
    conv_kernel<<<N_CBLK, 256, 0, stream>>>(u, wcvt, Cb, convb2, offs, rst, scr);
    scr_reduce_kernel<<<128, 128, 0, stream>>>(scr, scr2);
    bn_finalize_kernel<<<1, 1024, 0, stream>>>(scr2, gamma2, beta2, ss);
    head_prep_kernel<<<65, 256, 0, stream>>>(ss, head_w, head_b, wht, hb2);
    head_kernel<<<(N_TILES + 7)/8, 512, 0, stream>>>(rst, wht, hb2, x);
    pool_kernel<<<N_GRAPHS, 1024, 0, stream>>>(x, gstart, out);
    gather_kernel<<<(N_QUERY*HID + 255)/256, 256, 0, stream>>>(x, nidx, out + N_GRAPHS*HID);
}